// Round 3
// baseline (825.787 us; speedup 1.0000x reference)
//
#include <hip/hip_runtime.h>

// Instant-NGP hash encode (16 levels, F=2) + 32->64->64->8 MLP via MFMA,
// outer trilinear over 8 corners of a 512^3 grid.
//
// R3: MLP moved from scalar VALU (~210us floor) to mfma_f32_16x16x32_bf16.
// Transposed formulation D[out_feat][eval] = W^T x^T so that:
//   - B-operand: n = lane&15 = eval, k = (lane>>4)*8+j = input feature
//   - C/D:      col = lane&15 = eval, row = (lane>>4)*4+reg = output feature
// => inter-layer relayout stays within each lane's own eval row in LDS
// (4x ds_write_b64 + 2x ds_read_b128 per layer), no block barriers.
// Weights pre-swizzled to A-frag order (A[m=out][k=in] = W[k][m]) by prep_w
// into d_ws, hi/lo bf16 split (weight quant error ~0; 2x MFMA, negligible).
// Activations single bf16 (x, h1, h2): predicted absmax ~1e-6 < 2.3e-6.

typedef __attribute__((ext_vector_type(8))) short short8_t;
typedef __attribute__((ext_vector_type(4))) float f32x4;

static constexpr unsigned kT    = 1u << 19;
static constexpr unsigned kMask = kT - 1u;
static constexpr unsigned cP1   = 2654435761u;
static constexpr unsigned cP2   = 805459861u;
static constexpr int      BLOCK = 128;

static __device__ __forceinline__ unsigned bf16_rn(float x) {
    unsigned u = __float_as_uint(x);
    return (u + 0x7fffu + ((u >> 16) & 1u)) >> 16;   // round-to-nearest-even
}

static __device__ __forceinline__ f32x4 mfma16(short8_t a, short8_t b, f32x4 c) {
    return __builtin_amdgcn_mfma_f32_16x16x32_bf16(a, b, c, 0, 0, 0);
}

// ---- weight pre-swizzle: A-frag order, hi at ws[0,14336), lo at [14336,28672)
// tiles: 0..3 = W0 (mt = t); 4..11 = W1 (mt = (t-4)>>1, kt = (t-4)&1);
//        12..13 = W2 (kt = t-12, rows m>=8 zeroed).
// frag elem j of lane: W[kt*32 + (lane>>4)*8 + j][mt*16 + (lane&15)]
__global__ void prep_w(const float* __restrict__ W0, const float* __restrict__ W1,
                       const float* __restrict__ W2, uint4* __restrict__ ws)
{
    const int t = blockIdx.x, lane = threadIdx.x;
    const int n = lane & 15, q = lane >> 4;
    unsigned hi[4], lo[4];
    #pragma unroll
    for (int d = 0; d < 4; ++d) {
        unsigned h2[2], l2[2];
        #pragma unroll
        for (int s = 0; s < 2; ++s) {
            const int k = q * 8 + d * 2 + s;
            float v;
            if (t < 4)       v = W0[k * 64 + t * 16 + n];
            else if (t < 12) v = W1[(((t - 4) & 1) * 32 + k) * 64 + ((t - 4) >> 1) * 16 + n];
            else             v = (n < 8) ? W2[((t - 12) * 32 + k) * 8 + n] : 0.0f;
            const unsigned h = bf16_rn(v);
            h2[s] = h;
            l2[s] = bf16_rn(v - __uint_as_float(h << 16));
        }
        hi[d] = h2[0] | (h2[1] << 16);
        lo[d] = l2[0] | (l2[1] << 16);
    }
    ws[t * 64 + lane]       = make_uint4(hi[0], hi[1], hi[2], hi[3]);
    ws[896 + t * 64 + lane] = make_uint4(lo[0], lo[1], lo[2], lo[3]);
}

__global__ __launch_bounds__(BLOCK, 5)
void ngp_mfma(const float*  __restrict__ xyz,
              const float2* __restrict__ tbl,
              const int*    __restrict__ boundp,
              const unsigned* __restrict__ wsw,
              float*        __restrict__ out,
              int npts)
{
    // LDS dword layout: x: [0,2560) eval stride 20dw (80B, 16B-aligned, 2-way
    // bank max on reads); h: [2560,3712) per-wave 576dw, eval row 36dw (144B);
    // wb: [3712,3840).
    __shared__ __align__(16) unsigned lds[3840];
    const int tid  = threadIdx.x;
    const int lane = tid & 63;
    const int wv   = tid >> 6;

    // ================= encode (identical numerics to R2) =================
    const int ge = blockIdx.x * BLOCK + tid;
    const int pt = ge >> 3;
    const int b  = ge & 7;

    const float bnd = (float)boundp[0];
    const float sc  = 0.5f / bnd;

    const float pxv = xyz[pt * 3 + 0];
    const float pyv = xyz[pt * 3 + 1];
    const float pzv = xyz[pt * 3 + 2];

    const float cxf = (pxv + bnd) * sc * 512.0f;
    const float cyf = (pyv + bnd) * sc * 512.0f;
    const float czf = (pzv + bnd) * sc * 512.0f;

    const float c0x = fminf(fmaxf(floorf(cxf), 0.0f), 511.0f);
    const float c0y = fminf(fmaxf(floorf(cyf), 0.0f), 511.0f);
    const float c0z = fminf(fmaxf(floorf(czf), 0.0f), 511.0f);
    const float frx = cxf - c0x;
    const float fry = cyf - c0y;
    const float frz = czf - c0z;

    const unsigned kx = (unsigned)c0x + (unsigned)(b & 1);
    const unsigned ky = (unsigned)c0y + (unsigned)((b >> 1) & 1);
    const unsigned kz = (unsigned)c0z + (unsigned)((b >> 2) & 1);

    const float wb = ((b & 1) ? frx : 1.0f - frx)
                   * ((b & 2) ? fry : 1.0f - fry)
                   * ((b & 4) ? frz : 1.0f - frz);

    // fine levels (l=5..15): frac==0, single gather
    const unsigned kyp = ky * cP1;
    const unsigned kzp = kz * cP2;
    float2 gf[11];
    #pragma unroll
    for (int l = 5; l < 16; ++l) {
        const int s = l - 5;
        const unsigned idx = ((kx << s) ^ (kyp << s) ^ (kzp << s)) & kMask;
        gf[l - 5] = tbl[(size_t)l * kT + idx];
    }

    // hashed coarse (l=3,4): prefetch 16 gathers
    float2 gH[2][8];
    #pragma unroll
    for (int l = 3; l < 5; ++l) {
        const int d = 5 - l;
        const unsigned qx = kx >> d, qy = ky >> d, qz = kz >> d;
        const unsigned hy0 = qy * cP1, hy1 = hy0 + cP1;
        const unsigned hz0 = qz * cP2, hz1 = hz0 + cP2;
        const unsigned x1u = qx + 1u;
        const float2* __restrict__ base = tbl + (size_t)l * kT;
        gH[l - 3][0] = base[(qx  ^ hy0 ^ hz0) & kMask];
        gH[l - 3][1] = base[(x1u ^ hy0 ^ hz0) & kMask];
        gH[l - 3][2] = base[(qx  ^ hy1 ^ hz0) & kMask];
        gH[l - 3][3] = base[(x1u ^ hy1 ^ hz0) & kMask];
        gH[l - 3][4] = base[(qx  ^ hy0 ^ hz1) & kMask];
        gH[l - 3][5] = base[(x1u ^ hy0 ^ hz1) & kMask];
        gH[l - 3][6] = base[(qx  ^ hy1 ^ hz1) & kMask];
        gH[l - 3][7] = base[(x1u ^ hy1 ^ hz1) & kMask];
    }

    float2 gc[5];
    #pragma unroll
    for (int l = 0; l < 5; ++l) {
        const int d = 5 - l;
        const unsigned m = (1u << d) - 1u;
        const float inv = 1.0f / (float)(1 << d);
        const unsigned qx = kx >> d, qy = ky >> d, qz = kz >> d;
        const float fx = (float)(kx & m) * inv;
        const float fy = (float)(ky & m) * inv;
        const float fz = (float)(kz & m) * inv;
        float2 g0, g1, g2, g3, g4, g5, g6, g7;
        if (l < 3) {                     // dense, clamp to res
            const unsigned res = 16u << l;
            const unsigned R = res + 1u, R2 = R * R;
            const unsigned x0 = (qx < res ? qx : res);
            const unsigned x1 = (qx + 1u < res ? qx + 1u : res);
            const unsigned y0 = (qy < res ? qy : res) * R;
            const unsigned y1 = (qy + 1u < res ? qy + 1u : res) * R;
            const unsigned z0 = (qz < res ? qz : res) * R2;
            const unsigned z1 = (qz + 1u < res ? qz + 1u : res) * R2;
            const float2* __restrict__ base = tbl + (size_t)l * kT;
            g0 = base[x0 + y0 + z0]; g1 = base[x1 + y0 + z0];
            g2 = base[x0 + y1 + z0]; g3 = base[x1 + y1 + z0];
            g4 = base[x0 + y0 + z1]; g5 = base[x1 + y0 + z1];
            g6 = base[x0 + y1 + z1]; g7 = base[x1 + y1 + z1];
        } else {
            g0 = gH[l - 3][0]; g1 = gH[l - 3][1]; g2 = gH[l - 3][2]; g3 = gH[l - 3][3];
            g4 = gH[l - 3][4]; g5 = gH[l - 3][5]; g6 = gH[l - 3][6]; g7 = gH[l - 3][7];
        }
        const float wx1 = fx, wx0 = 1.0f - fx;
        const float wy1 = fy, wy0 = 1.0f - fy;
        const float wz1 = fz, wz0 = 1.0f - fz;
        const float w00 = wx0 * wy0, w10 = wx1 * wy0, w01 = wx0 * wy1, w11 = wx1 * wy1;
        const float a0 = w00 * wz0, a1 = w10 * wz0, a2 = w01 * wz0, a3 = w11 * wz0;
        const float a4 = w00 * wz1, a5 = w10 * wz1, a6 = w01 * wz1, a7 = w11 * wz1;
        float vx = a0 * g0.x + a1 * g1.x + a2 * g2.x + a3 * g3.x
                 + a4 * g4.x + a5 * g5.x + a6 * g6.x + a7 * g7.x;
        float vy = a0 * g0.y + a1 * g1.y + a2 * g2.y + a3 * g3.y
                 + a4 * g4.y + a5 * g5.y + a6 * g6.y + a7 * g7.y;
        gc[l] = make_float2(vx, vy);
    }

    // pack features: dword l = (bf16(f_{2l}), bf16(f_{2l+1}))
    unsigned xd[16];
    #pragma unroll
    for (int l = 0; l < 16; ++l) {
        const float2 v = (l < 5) ? gc[l] : gf[l - 5];
        xd[l] = bf16_rn(v.x) | (bf16_rn(v.y) << 16);
    }
    uint4* xr = (uint4*)(lds + tid * 20);
    xr[0] = make_uint4(xd[0],  xd[1],  xd[2],  xd[3]);
    xr[1] = make_uint4(xd[4],  xd[5],  xd[6],  xd[7]);
    xr[2] = make_uint4(xd[8],  xd[9],  xd[10], xd[11]);
    xr[3] = make_uint4(xd[12], xd[13], xd[14], xd[15]);
    lds[3712 + tid] = __float_as_uint(wb);
    __threadfence_block();   // x/wb visible to all lanes of this wave

    // ================= MLP (transposed, MFMA) =================
    const short8_t* wHi = (const short8_t*)wsw;
    const short8_t* wLo = (const short8_t*)(wsw + 3584);   // +14336 B
    const int col = lane & 15;          // = eval within group = MFMA col
    const int q   = lane >> 4;
    unsigned* hrow = lds + 2560 + wv * 576 + col * 36;
    const f32x4 zero = {0.0f, 0.0f, 0.0f, 0.0f};

    #pragma unroll 1
    for (int g = 0; g < 4; ++g) {
        const int ev = wv * 64 + g * 16 + col;
        const short8_t xb = *(const short8_t*)(lds + ev * 20 + q * 4);

        unsigned hp0[4], hp1[4];
        // layer 1: h1[mt*16+q*4+r][ev]
        #pragma unroll
        for (int mt = 0; mt < 4; ++mt) {
            f32x4 a = mfma16(wLo[mt * 64 + lane], xb, zero);
            a = mfma16(wHi[mt * 64 + lane], xb, a);
            hp0[mt] = bf16_rn(fmaxf(a[0], 0.0f)) | (bf16_rn(fmaxf(a[1], 0.0f)) << 16);
            hp1[mt] = bf16_rn(fmaxf(a[2], 0.0f)) | (bf16_rn(fmaxf(a[3], 0.0f)) << 16);
        }
        #pragma unroll
        for (int mt = 0; mt < 4; ++mt)
            *(uint2*)(hrow + mt * 8 + q * 2) = make_uint2(hp0[mt], hp1[mt]);
        __threadfence_block();
        short8_t bk0 = *(const short8_t*)(hrow + q * 4);        // feats q*8..+7
        short8_t bk1 = *(const short8_t*)(hrow + 16 + q * 4);   // feats 32+q*8..

        // layer 2
        #pragma unroll
        for (int mt = 0; mt < 4; ++mt) {
            f32x4 a = mfma16(wLo[(4 + mt * 2) * 64 + lane], bk0, zero);
            a = mfma16(wHi[(4 + mt * 2) * 64 + lane], bk0, a);
            a = mfma16(wLo[(5 + mt * 2) * 64 + lane], bk1, a);
            a = mfma16(wHi[(5 + mt * 2) * 64 + lane], bk1, a);
            hp0[mt] = bf16_rn(fmaxf(a[0], 0.0f)) | (bf16_rn(fmaxf(a[1], 0.0f)) << 16);
            hp1[mt] = bf16_rn(fmaxf(a[2], 0.0f)) | (bf16_rn(fmaxf(a[3], 0.0f)) << 16);
        }
        #pragma unroll
        for (int mt = 0; mt < 4; ++mt)
            *(uint2*)(hrow + mt * 8 + q * 2) = make_uint2(hp0[mt], hp1[mt]);
        __threadfence_block();
        bk0 = *(const short8_t*)(hrow + q * 4);
        bk1 = *(const short8_t*)(hrow + 16 + q * 4);

        // layer 3: out[q*4+r][ev] (rows 8..15 are zero-padded W2)
        f32x4 a3 = mfma16(wLo[12 * 64 + lane], bk0, zero);
        a3 = mfma16(wHi[12 * 64 + lane], bk0, a3);
        a3 = mfma16(wLo[13 * 64 + lane], bk1, a3);
        a3 = mfma16(wHi[13 * 64 + lane], bk1, a3);

        // weight by wb and reduce over the 8 corners (eval low 3 bits)
        const float wbv = __uint_as_float(lds[3712 + ev]);
        float v0 = wbv * a3[0], v1 = wbv * a3[1], v2 = wbv * a3[2], v3 = wbv * a3[3];
        #pragma unroll
        for (int s = 1; s < 8; s <<= 1) {
            v0 += __shfl_xor(v0, s);
            v1 += __shfl_xor(v1, s);
            v2 += __shfl_xor(v2, s);
            v3 += __shfl_xor(v3, s);
        }
        if (((lane & 7) == 0) && q < 2) {
            const int p = (blockIdx.x * BLOCK + ev) >> 3;
            *(float4*)(out + p * 8 + q * 4) = make_float4(v0, v1, v2, v3);
        }
        __threadfence_block();   // h-row reuse ordering for next g
    }
}

extern "C" void kernel_launch(void* const* d_in, const int* in_sizes, int n_in,
                              void* d_out, int out_size, void* d_ws, size_t ws_size,
                              hipStream_t stream) {
    const float*  xyz = (const float*)d_in[0];
    const float2* tbl = (const float2*)d_in[1];
    const float*  W0  = (const float*)d_in[2];
    const float*  W1  = (const float*)d_in[3];
    const float*  W2  = (const float*)d_in[4];
    const int*    bnd = (const int*)d_in[5];
    float* out = (float*)d_out;

    const int npts  = in_sizes[0] / 3;
    const int total = npts * 8;
    const int grid  = total / BLOCK;

    hipLaunchKernelGGL(prep_w, dim3(14), dim3(64), 0, stream,
                       W0, W1, W2, (uint4*)d_ws);
    hipLaunchKernelGGL(ngp_mfma, dim3(grid), dim3(BLOCK), 0, stream,
                       xyz, tbl, bnd, (const unsigned*)d_ws, out, npts);
}

// Round 4
// 487.156 us; speedup vs baseline: 1.6951x; 1.6951x over previous
//
#include <hip/hip_runtime.h>

// Instant-NGP hash encode (16 levels, F=2) + 32->64->64->8 MLP via MFMA,
// outer trilinear over 8 corners of a 512^3 grid.
//
// R3: MLP on mfma_f32_16x16x32_bf16, transposed D[out][eval]; weights
//     pre-swizzled to A-frag order in d_ws with hi/lo bf16 split (exact).
// R4: launch_bounds (128,5)->(128,4). R3's VGPR cap (102) starved the
//     allocator: WRITE_SIZE 696 MB / FETCH 2.2 GB of scratch spill traffic
//     (out is 8 MB). Cap 128 fits the ~100-reg encode live set; occupancy
//     VGPR-bound at 16 waves/CU instead of spill-bound.

typedef __attribute__((ext_vector_type(8))) short short8_t;
typedef __attribute__((ext_vector_type(4))) float f32x4;

static constexpr unsigned kT    = 1u << 19;
static constexpr unsigned kMask = kT - 1u;
static constexpr unsigned cP1   = 2654435761u;
static constexpr unsigned cP2   = 805459861u;
static constexpr int      BLOCK = 128;

static __device__ __forceinline__ unsigned bf16_rn(float x) {
    unsigned u = __float_as_uint(x);
    return (u + 0x7fffu + ((u >> 16) & 1u)) >> 16;   // round-to-nearest-even
}

static __device__ __forceinline__ f32x4 mfma16(short8_t a, short8_t b, f32x4 c) {
    return __builtin_amdgcn_mfma_f32_16x16x32_bf16(a, b, c, 0, 0, 0);
}

// ---- weight pre-swizzle: A-frag order, hi at ws[0,14336), lo at [14336,28672)
// tiles: 0..3 = W0 (mt = t); 4..11 = W1 (mt = (t-4)>>1, kt = (t-4)&1);
//        12..13 = W2 (kt = t-12, rows m>=8 zeroed).
// frag elem j of lane: W[kt*32 + (lane>>4)*8 + j][mt*16 + (lane&15)]
__global__ void prep_w(const float* __restrict__ W0, const float* __restrict__ W1,
                       const float* __restrict__ W2, uint4* __restrict__ ws)
{
    const int t = blockIdx.x, lane = threadIdx.x;
    const int n = lane & 15, q = lane >> 4;
    unsigned hi[4], lo[4];
    #pragma unroll
    for (int d = 0; d < 4; ++d) {
        unsigned h2[2], l2[2];
        #pragma unroll
        for (int s = 0; s < 2; ++s) {
            const int k = q * 8 + d * 2 + s;
            float v;
            if (t < 4)       v = W0[k * 64 + t * 16 + n];
            else if (t < 12) v = W1[(((t - 4) & 1) * 32 + k) * 64 + ((t - 4) >> 1) * 16 + n];
            else             v = (n < 8) ? W2[((t - 12) * 32 + k) * 8 + n] : 0.0f;
            const unsigned h = bf16_rn(v);
            h2[s] = h;
            l2[s] = bf16_rn(v - __uint_as_float(h << 16));
        }
        hi[d] = h2[0] | (h2[1] << 16);
        lo[d] = l2[0] | (l2[1] << 16);
    }
    ws[t * 64 + lane]       = make_uint4(hi[0], hi[1], hi[2], hi[3]);
    ws[896 + t * 64 + lane] = make_uint4(lo[0], lo[1], lo[2], lo[3]);
}

__global__ __launch_bounds__(BLOCK, 4)
void ngp_mfma(const float*  __restrict__ xyz,
              const float2* __restrict__ tbl,
              const int*    __restrict__ boundp,
              const unsigned* __restrict__ wsw,
              float*        __restrict__ out,
              int npts)
{
    // LDS dword layout: x: [0,2560) eval stride 20dw (80B, 16B-aligned);
    // h: [2560,3712) per-wave 576dw, eval row 36dw; wb: [3712,3840).
    __shared__ __align__(16) unsigned lds[3840];
    const int tid  = threadIdx.x;
    const int lane = tid & 63;
    const int wv   = tid >> 6;

    // ================= encode (identical numerics to R2) =================
    const int ge = blockIdx.x * BLOCK + tid;
    const int pt = ge >> 3;
    const int b  = ge & 7;

    const float bnd = (float)boundp[0];
    const float sc  = 0.5f / bnd;

    const float pxv = xyz[pt * 3 + 0];
    const float pyv = xyz[pt * 3 + 1];
    const float pzv = xyz[pt * 3 + 2];

    const float cxf = (pxv + bnd) * sc * 512.0f;
    const float cyf = (pyv + bnd) * sc * 512.0f;
    const float czf = (pzv + bnd) * sc * 512.0f;

    const float c0x = fminf(fmaxf(floorf(cxf), 0.0f), 511.0f);
    const float c0y = fminf(fmaxf(floorf(cyf), 0.0f), 511.0f);
    const float c0z = fminf(fmaxf(floorf(czf), 0.0f), 511.0f);
    const float frx = cxf - c0x;
    const float fry = cyf - c0y;
    const float frz = czf - c0z;

    const unsigned kx = (unsigned)c0x + (unsigned)(b & 1);
    const unsigned ky = (unsigned)c0y + (unsigned)((b >> 1) & 1);
    const unsigned kz = (unsigned)c0z + (unsigned)((b >> 2) & 1);

    const float wb = ((b & 1) ? frx : 1.0f - frx)
                   * ((b & 2) ? fry : 1.0f - fry)
                   * ((b & 4) ? frz : 1.0f - frz);

    // fine levels (l=5..15): frac==0, single gather
    const unsigned kyp = ky * cP1;
    const unsigned kzp = kz * cP2;
    float2 gf[11];
    #pragma unroll
    for (int l = 5; l < 16; ++l) {
        const int s = l - 5;
        const unsigned idx = ((kx << s) ^ (kyp << s) ^ (kzp << s)) & kMask;
        gf[l - 5] = tbl[(size_t)l * kT + idx];
    }

    // hashed coarse (l=3,4): prefetch 16 gathers
    float2 gH[2][8];
    #pragma unroll
    for (int l = 3; l < 5; ++l) {
        const int d = 5 - l;
        const unsigned qx = kx >> d, qy = ky >> d, qz = kz >> d;
        const unsigned hy0 = qy * cP1, hy1 = hy0 + cP1;
        const unsigned hz0 = qz * cP2, hz1 = hz0 + cP2;
        const unsigned x1u = qx + 1u;
        const float2* __restrict__ base = tbl + (size_t)l * kT;
        gH[l - 3][0] = base[(qx  ^ hy0 ^ hz0) & kMask];
        gH[l - 3][1] = base[(x1u ^ hy0 ^ hz0) & kMask];
        gH[l - 3][2] = base[(qx  ^ hy1 ^ hz0) & kMask];
        gH[l - 3][3] = base[(x1u ^ hy1 ^ hz0) & kMask];
        gH[l - 3][4] = base[(qx  ^ hy0 ^ hz1) & kMask];
        gH[l - 3][5] = base[(x1u ^ hy0 ^ hz1) & kMask];
        gH[l - 3][6] = base[(qx  ^ hy1 ^ hz1) & kMask];
        gH[l - 3][7] = base[(x1u ^ hy1 ^ hz1) & kMask];
    }

    float2 gc[5];
    #pragma unroll
    for (int l = 0; l < 5; ++l) {
        const int d = 5 - l;
        const unsigned m = (1u << d) - 1u;
        const float inv = 1.0f / (float)(1 << d);
        const unsigned qx = kx >> d, qy = ky >> d, qz = kz >> d;
        const float fx = (float)(kx & m) * inv;
        const float fy = (float)(ky & m) * inv;
        const float fz = (float)(kz & m) * inv;
        float2 g0, g1, g2, g3, g4, g5, g6, g7;
        if (l < 3) {                     // dense, clamp to res
            const unsigned res = 16u << l;
            const unsigned R = res + 1u, R2 = R * R;
            const unsigned x0 = (qx < res ? qx : res);
            const unsigned x1 = (qx + 1u < res ? qx + 1u : res);
            const unsigned y0 = (qy < res ? qy : res) * R;
            const unsigned y1 = (qy + 1u < res ? qy + 1u : res) * R;
            const unsigned z0 = (qz < res ? qz : res) * R2;
            const unsigned z1 = (qz + 1u < res ? qz + 1u : res) * R2;
            const float2* __restrict__ base = tbl + (size_t)l * kT;
            g0 = base[x0 + y0 + z0]; g1 = base[x1 + y0 + z0];
            g2 = base[x0 + y1 + z0]; g3 = base[x1 + y1 + z0];
            g4 = base[x0 + y0 + z1]; g5 = base[x1 + y0 + z1];
            g6 = base[x0 + y1 + z1]; g7 = base[x1 + y1 + z1];
        } else {
            g0 = gH[l - 3][0]; g1 = gH[l - 3][1]; g2 = gH[l - 3][2]; g3 = gH[l - 3][3];
            g4 = gH[l - 3][4]; g5 = gH[l - 3][5]; g6 = gH[l - 3][6]; g7 = gH[l - 3][7];
        }
        const float wx1 = fx, wx0 = 1.0f - fx;
        const float wy1 = fy, wy0 = 1.0f - fy;
        const float wz1 = fz, wz0 = 1.0f - fz;
        const float w00 = wx0 * wy0, w10 = wx1 * wy0, w01 = wx0 * wy1, w11 = wx1 * wy1;
        const float a0 = w00 * wz0, a1 = w10 * wz0, a2 = w01 * wz0, a3 = w11 * wz0;
        const float a4 = w00 * wz1, a5 = w10 * wz1, a6 = w01 * wz1, a7 = w11 * wz1;
        float vx = a0 * g0.x + a1 * g1.x + a2 * g2.x + a3 * g3.x
                 + a4 * g4.x + a5 * g5.x + a6 * g6.x + a7 * g7.x;
        float vy = a0 * g0.y + a1 * g1.y + a2 * g2.y + a3 * g3.y
                 + a4 * g4.y + a5 * g5.y + a6 * g6.y + a7 * g7.y;
        gc[l] = make_float2(vx, vy);
    }

    // pack features: dword l = (bf16(f_{2l}), bf16(f_{2l+1}))
    unsigned xd[16];
    #pragma unroll
    for (int l = 0; l < 16; ++l) {
        const float2 v = (l < 5) ? gc[l] : gf[l - 5];
        xd[l] = bf16_rn(v.x) | (bf16_rn(v.y) << 16);
    }
    uint4* xr = (uint4*)(lds + tid * 20);
    xr[0] = make_uint4(xd[0],  xd[1],  xd[2],  xd[3]);
    xr[1] = make_uint4(xd[4],  xd[5],  xd[6],  xd[7]);
    xr[2] = make_uint4(xd[8],  xd[9],  xd[10], xd[11]);
    xr[3] = make_uint4(xd[12], xd[13], xd[14], xd[15]);
    lds[3712 + tid] = __float_as_uint(wb);
    __threadfence_block();   // x/wb visible to all lanes of this wave

    // ================= MLP (transposed, MFMA) =================
    const short8_t* wHi = (const short8_t*)wsw;
    const short8_t* wLo = (const short8_t*)(wsw + 3584);   // +14336 B
    const int col = lane & 15;          // = eval within group = MFMA col
    const int q   = lane >> 4;
    unsigned* hrow = lds + 2560 + wv * 576 + col * 36;
    const f32x4 zero = {0.0f, 0.0f, 0.0f, 0.0f};

    #pragma unroll 1
    for (int g = 0; g < 4; ++g) {
        const int ev = wv * 64 + g * 16 + col;
        const short8_t xb = *(const short8_t*)(lds + ev * 20 + q * 4);

        unsigned hp0[4], hp1[4];
        // layer 1: h1[mt*16+q*4+r][ev]
        #pragma unroll
        for (int mt = 0; mt < 4; ++mt) {
            f32x4 a = mfma16(wLo[mt * 64 + lane], xb, zero);
            a = mfma16(wHi[mt * 64 + lane], xb, a);
            hp0[mt] = bf16_rn(fmaxf(a[0], 0.0f)) | (bf16_rn(fmaxf(a[1], 0.0f)) << 16);
            hp1[mt] = bf16_rn(fmaxf(a[2], 0.0f)) | (bf16_rn(fmaxf(a[3], 0.0f)) << 16);
        }
        #pragma unroll
        for (int mt = 0; mt < 4; ++mt)
            *(uint2*)(hrow + mt * 8 + q * 2) = make_uint2(hp0[mt], hp1[mt]);
        __threadfence_block();
        short8_t bk0 = *(const short8_t*)(hrow + q * 4);        // feats q*8..+7
        short8_t bk1 = *(const short8_t*)(hrow + 16 + q * 4);   // feats 32+q*8..

        // layer 2
        #pragma unroll
        for (int mt = 0; mt < 4; ++mt) {
            f32x4 a = mfma16(wLo[(4 + mt * 2) * 64 + lane], bk0, zero);
            a = mfma16(wHi[(4 + mt * 2) * 64 + lane], bk0, a);
            a = mfma16(wLo[(5 + mt * 2) * 64 + lane], bk1, a);
            a = mfma16(wHi[(5 + mt * 2) * 64 + lane], bk1, a);
            hp0[mt] = bf16_rn(fmaxf(a[0], 0.0f)) | (bf16_rn(fmaxf(a[1], 0.0f)) << 16);
            hp1[mt] = bf16_rn(fmaxf(a[2], 0.0f)) | (bf16_rn(fmaxf(a[3], 0.0f)) << 16);
        }
        #pragma unroll
        for (int mt = 0; mt < 4; ++mt)
            *(uint2*)(hrow + mt * 8 + q * 2) = make_uint2(hp0[mt], hp1[mt]);
        __threadfence_block();
        bk0 = *(const short8_t*)(hrow + q * 4);
        bk1 = *(const short8_t*)(hrow + 16 + q * 4);

        // layer 3: out[q*4+r][ev] (rows 8..15 are zero-padded W2)
        f32x4 a3 = mfma16(wLo[12 * 64 + lane], bk0, zero);
        a3 = mfma16(wHi[12 * 64 + lane], bk0, a3);
        a3 = mfma16(wLo[13 * 64 + lane], bk1, a3);
        a3 = mfma16(wHi[13 * 64 + lane], bk1, a3);

        // weight by wb and reduce over the 8 corners (eval low 3 bits)
        const float wbv = __uint_as_float(lds[3712 + ev]);
        float v0 = wbv * a3[0], v1 = wbv * a3[1], v2 = wbv * a3[2], v3 = wbv * a3[3];
        #pragma unroll
        for (int s = 1; s < 8; s <<= 1) {
            v0 += __shfl_xor(v0, s);
            v1 += __shfl_xor(v1, s);
            v2 += __shfl_xor(v2, s);
            v3 += __shfl_xor(v3, s);
        }
        if (((lane & 7) == 0) && q < 2) {
            const int p = (blockIdx.x * BLOCK + ev) >> 3;
            *(float4*)(out + p * 8 + q * 4) = make_float4(v0, v1, v2, v3);
        }
        __threadfence_block();   // h-row reuse ordering for next g
    }
}

extern "C" void kernel_launch(void* const* d_in, const int* in_sizes, int n_in,
                              void* d_out, int out_size, void* d_ws, size_t ws_size,
                              hipStream_t stream) {
    const float*  xyz = (const float*)d_in[0];
    const float2* tbl = (const float2*)d_in[1];
    const float*  W0  = (const float*)d_in[2];
    const float*  W1  = (const float*)d_in[3];
    const float*  W2  = (const float*)d_in[4];
    const int*    bnd = (const int*)d_in[5];
    float* out = (float*)d_out;

    const int npts  = in_sizes[0] / 3;
    const int total = npts * 8;
    const int grid  = total / BLOCK;

    hipLaunchKernelGGL(prep_w, dim3(14), dim3(64), 0, stream,
                       W0, W1, W2, (uint4*)d_ws);
    hipLaunchKernelGGL(ngp_mfma, dim3(grid), dim3(BLOCK), 0, stream,
                       xyz, tbl, bnd, (const unsigned*)d_ws, out, npts);
}

// Round 5
// 383.386 us; speedup vs baseline: 2.1539x; 1.2707x over previous
//
#include <hip/hip_runtime.h>

// Instant-NGP hash encode (16 levels, F=2) + 32->64->64->8 MLP via MFMA,
// outer trilinear over 8 corners of a 512^3 grid.
//
// R3: MLP on mfma_f32_16x16x32_bf16, transposed D[out][eval]; weights
//     pre-swizzled to A-frag order in d_ws.
// R4: launch_bounds (128,5)->(128,4): cut spill 696->165 MB, 735->393us.
// R5: single-bf16 weights (was hi/lo split: 22 frags = 88 VGPRs hoisted
//     out of the g-loop caused the remaining spill). 14 frags = 56 VGPRs,
//     preloaded ONCE into registers after encode regs die; MLP loop has
//     zero VMEM. Predicted WRITE_SIZE -> ~8 MB (no spill), absmax ~1e-6.

typedef __attribute__((ext_vector_type(8))) short short8_t;
typedef __attribute__((ext_vector_type(4))) float f32x4;

static constexpr unsigned kT    = 1u << 19;
static constexpr unsigned kMask = kT - 1u;
static constexpr unsigned cP1   = 2654435761u;
static constexpr unsigned cP2   = 805459861u;
static constexpr int      BLOCK = 128;

static __device__ __forceinline__ unsigned bf16_rn(float x) {
    unsigned u = __float_as_uint(x);
    return (u + 0x7fffu + ((u >> 16) & 1u)) >> 16;   // round-to-nearest-even
}

static __device__ __forceinline__ f32x4 mfma16(short8_t a, short8_t b, f32x4 c) {
    return __builtin_amdgcn_mfma_f32_16x16x32_bf16(a, b, c, 0, 0, 0);
}

// ---- weight pre-swizzle: A-frag order, bf16 RNE, 14 tiles x 64 lanes x 16B.
// tiles: 0..3 = W0 (mt = t); 4..11 = W1 (mt = (t-4)>>1, kt = (t-4)&1);
//        12..13 = W2 (kt = t-12, rows m>=8 zeroed).
// frag elem j of lane: W[kt*32 + (lane>>4)*8 + j][mt*16 + (lane&15)]
__global__ void prep_w(const float* __restrict__ W0, const float* __restrict__ W1,
                       const float* __restrict__ W2, uint4* __restrict__ ws)
{
    const int t = blockIdx.x, lane = threadIdx.x;
    const int n = lane & 15, q = lane >> 4;
    unsigned hi[4];
    #pragma unroll
    for (int d = 0; d < 4; ++d) {
        unsigned h2[2];
        #pragma unroll
        for (int s = 0; s < 2; ++s) {
            const int k = q * 8 + d * 2 + s;
            float v;
            if (t < 4)       v = W0[k * 64 + t * 16 + n];
            else if (t < 12) v = W1[(((t - 4) & 1) * 32 + k) * 64 + ((t - 4) >> 1) * 16 + n];
            else             v = (n < 8) ? W2[((t - 12) * 32 + k) * 8 + n] : 0.0f;
            h2[s] = bf16_rn(v);
        }
        hi[d] = h2[0] | (h2[1] << 16);
    }
    ws[t * 64 + lane] = make_uint4(hi[0], hi[1], hi[2], hi[3]);
}

__global__ __launch_bounds__(BLOCK, 4)
void ngp_mfma(const float*  __restrict__ xyz,
              const float2* __restrict__ tbl,
              const int*    __restrict__ boundp,
              const unsigned* __restrict__ wsw,
              float*        __restrict__ out,
              int npts)
{
    // LDS dword layout: x: [0,2560) eval stride 20dw (80B, 16B-aligned);
    // h: [2560,3712) per-wave 576dw, eval row 36dw; wb: [3712,3840).
    __shared__ __align__(16) unsigned lds[3840];
    const int tid  = threadIdx.x;
    const int lane = tid & 63;
    const int wv   = tid >> 6;

    // ================= encode (identical numerics to R2) =================
    const int ge = blockIdx.x * BLOCK + tid;
    const int pt = ge >> 3;
    const int b  = ge & 7;

    const float bnd = (float)boundp[0];
    const float sc  = 0.5f / bnd;

    const float pxv = xyz[pt * 3 + 0];
    const float pyv = xyz[pt * 3 + 1];
    const float pzv = xyz[pt * 3 + 2];

    const float cxf = (pxv + bnd) * sc * 512.0f;
    const float cyf = (pyv + bnd) * sc * 512.0f;
    const float czf = (pzv + bnd) * sc * 512.0f;

    const float c0x = fminf(fmaxf(floorf(cxf), 0.0f), 511.0f);
    const float c0y = fminf(fmaxf(floorf(cyf), 0.0f), 511.0f);
    const float c0z = fminf(fmaxf(floorf(czf), 0.0f), 511.0f);
    const float frx = cxf - c0x;
    const float fry = cyf - c0y;
    const float frz = czf - c0z;

    const unsigned kx = (unsigned)c0x + (unsigned)(b & 1);
    const unsigned ky = (unsigned)c0y + (unsigned)((b >> 1) & 1);
    const unsigned kz = (unsigned)c0z + (unsigned)((b >> 2) & 1);

    const float wb = ((b & 1) ? frx : 1.0f - frx)
                   * ((b & 2) ? fry : 1.0f - fry)
                   * ((b & 4) ? frz : 1.0f - frz);

    // fine levels (l=5..15): frac==0, single gather
    const unsigned kyp = ky * cP1;
    const unsigned kzp = kz * cP2;
    float2 gf[11];
    #pragma unroll
    for (int l = 5; l < 16; ++l) {
        const int s = l - 5;
        const unsigned idx = ((kx << s) ^ (kyp << s) ^ (kzp << s)) & kMask;
        gf[l - 5] = tbl[(size_t)l * kT + idx];
    }

    // hashed coarse (l=3,4): prefetch 16 gathers
    float2 gH[2][8];
    #pragma unroll
    for (int l = 3; l < 5; ++l) {
        const int d = 5 - l;
        const unsigned qx = kx >> d, qy = ky >> d, qz = kz >> d;
        const unsigned hy0 = qy * cP1, hy1 = hy0 + cP1;
        const unsigned hz0 = qz * cP2, hz1 = hz0 + cP2;
        const unsigned x1u = qx + 1u;
        const float2* __restrict__ base = tbl + (size_t)l * kT;
        gH[l - 3][0] = base[(qx  ^ hy0 ^ hz0) & kMask];
        gH[l - 3][1] = base[(x1u ^ hy0 ^ hz0) & kMask];
        gH[l - 3][2] = base[(qx  ^ hy1 ^ hz0) & kMask];
        gH[l - 3][3] = base[(x1u ^ hy1 ^ hz0) & kMask];
        gH[l - 3][4] = base[(qx  ^ hy0 ^ hz1) & kMask];
        gH[l - 3][5] = base[(x1u ^ hy0 ^ hz1) & kMask];
        gH[l - 3][6] = base[(qx  ^ hy1 ^ hz1) & kMask];
        gH[l - 3][7] = base[(x1u ^ hy1 ^ hz1) & kMask];
    }

    float2 gc[5];
    #pragma unroll
    for (int l = 0; l < 5; ++l) {
        const int d = 5 - l;
        const unsigned m = (1u << d) - 1u;
        const float inv = 1.0f / (float)(1 << d);
        const unsigned qx = kx >> d, qy = ky >> d, qz = kz >> d;
        const float fx = (float)(kx & m) * inv;
        const float fy = (float)(ky & m) * inv;
        const float fz = (float)(kz & m) * inv;
        float2 g0, g1, g2, g3, g4, g5, g6, g7;
        if (l < 3) {                     // dense, clamp to res
            const unsigned res = 16u << l;
            const unsigned R = res + 1u, R2 = R * R;
            const unsigned x0 = (qx < res ? qx : res);
            const unsigned x1 = (qx + 1u < res ? qx + 1u : res);
            const unsigned y0 = (qy < res ? qy : res) * R;
            const unsigned y1 = (qy + 1u < res ? qy + 1u : res) * R;
            const unsigned z0 = (qz < res ? qz : res) * R2;
            const unsigned z1 = (qz + 1u < res ? qz + 1u : res) * R2;
            const float2* __restrict__ base = tbl + (size_t)l * kT;
            g0 = base[x0 + y0 + z0]; g1 = base[x1 + y0 + z0];
            g2 = base[x0 + y1 + z0]; g3 = base[x1 + y1 + z0];
            g4 = base[x0 + y0 + z1]; g5 = base[x1 + y0 + z1];
            g6 = base[x0 + y1 + z1]; g7 = base[x1 + y1 + z1];
        } else {
            g0 = gH[l - 3][0]; g1 = gH[l - 3][1]; g2 = gH[l - 3][2]; g3 = gH[l - 3][3];
            g4 = gH[l - 3][4]; g5 = gH[l - 3][5]; g6 = gH[l - 3][6]; g7 = gH[l - 3][7];
        }
        const float wx1 = fx, wx0 = 1.0f - fx;
        const float wy1 = fy, wy0 = 1.0f - fy;
        const float wz1 = fz, wz0 = 1.0f - fz;
        const float w00 = wx0 * wy0, w10 = wx1 * wy0, w01 = wx0 * wy1, w11 = wx1 * wy1;
        const float a0 = w00 * wz0, a1 = w10 * wz0, a2 = w01 * wz0, a3 = w11 * wz0;
        const float a4 = w00 * wz1, a5 = w10 * wz1, a6 = w01 * wz1, a7 = w11 * wz1;
        float vx = a0 * g0.x + a1 * g1.x + a2 * g2.x + a3 * g3.x
                 + a4 * g4.x + a5 * g5.x + a6 * g6.x + a7 * g7.x;
        float vy = a0 * g0.y + a1 * g1.y + a2 * g2.y + a3 * g3.y
                 + a4 * g4.y + a5 * g5.y + a6 * g6.y + a7 * g7.y;
        gc[l] = make_float2(vx, vy);
    }

    // pack features: dword l = (bf16(f_{2l}), bf16(f_{2l+1}))
    unsigned xd[16];
    #pragma unroll
    for (int l = 0; l < 16; ++l) {
        const float2 v = (l < 5) ? gc[l] : gf[l - 5];
        xd[l] = bf16_rn(v.x) | (bf16_rn(v.y) << 16);
    }
    uint4* xr = (uint4*)(lds + tid * 20);
    xr[0] = make_uint4(xd[0],  xd[1],  xd[2],  xd[3]);
    xr[1] = make_uint4(xd[4],  xd[5],  xd[6],  xd[7]);
    xr[2] = make_uint4(xd[8],  xd[9],  xd[10], xd[11]);
    xr[3] = make_uint4(xd[12], xd[13], xd[14], xd[15]);
    lds[3712 + tid] = __float_as_uint(wb);
    __threadfence_block();   // x/wb visible to all lanes of this wave

    // ===== preload all 14 weight fragments (encode regs are dead now) =====
    const short8_t* wf = (const short8_t*)wsw;
    short8_t w[14];
    #pragma unroll
    for (int t = 0; t < 14; ++t) w[t] = wf[t * 64 + lane];

    // ================= MLP (transposed, MFMA) =================
    const int col = lane & 15;          // = eval within group = MFMA col
    const int q   = lane >> 4;
    unsigned* hrow = lds + 2560 + wv * 576 + col * 36;
    const f32x4 zero = {0.0f, 0.0f, 0.0f, 0.0f};

    #pragma unroll 1
    for (int g = 0; g < 4; ++g) {
        const int ev = wv * 64 + g * 16 + col;
        const short8_t xb = *(const short8_t*)(lds + ev * 20 + q * 4);

        unsigned hp0[4], hp1[4];
        // layer 1: h1[mt*16+q*4+r][ev]
        #pragma unroll
        for (int mt = 0; mt < 4; ++mt) {
            f32x4 a = mfma16(w[mt], xb, zero);
            hp0[mt] = bf16_rn(fmaxf(a[0], 0.0f)) | (bf16_rn(fmaxf(a[1], 0.0f)) << 16);
            hp1[mt] = bf16_rn(fmaxf(a[2], 0.0f)) | (bf16_rn(fmaxf(a[3], 0.0f)) << 16);
        }
        #pragma unroll
        for (int mt = 0; mt < 4; ++mt)
            *(uint2*)(hrow + mt * 8 + q * 2) = make_uint2(hp0[mt], hp1[mt]);
        __threadfence_block();
        short8_t bk0 = *(const short8_t*)(hrow + q * 4);        // feats q*8..+7
        short8_t bk1 = *(const short8_t*)(hrow + 16 + q * 4);   // feats 32+q*8..

        // layer 2
        #pragma unroll
        for (int mt = 0; mt < 4; ++mt) {
            f32x4 a = mfma16(w[4 + mt * 2], bk0, zero);
            a = mfma16(w[5 + mt * 2], bk1, a);
            hp0[mt] = bf16_rn(fmaxf(a[0], 0.0f)) | (bf16_rn(fmaxf(a[1], 0.0f)) << 16);
            hp1[mt] = bf16_rn(fmaxf(a[2], 0.0f)) | (bf16_rn(fmaxf(a[3], 0.0f)) << 16);
        }
        #pragma unroll
        for (int mt = 0; mt < 4; ++mt)
            *(uint2*)(hrow + mt * 8 + q * 2) = make_uint2(hp0[mt], hp1[mt]);
        __threadfence_block();
        bk0 = *(const short8_t*)(hrow + q * 4);
        bk1 = *(const short8_t*)(hrow + 16 + q * 4);

        // layer 3: out[q*4+r][ev] (rows 8..15 are zero-padded W2)
        f32x4 a3 = mfma16(w[12], bk0, zero);
        a3 = mfma16(w[13], bk1, a3);

        // weight by wb and reduce over the 8 corners (eval low 3 bits)
        const float wbv = __uint_as_float(lds[3712 + ev]);
        float v0 = wbv * a3[0], v1 = wbv * a3[1], v2 = wbv * a3[2], v3 = wbv * a3[3];
        #pragma unroll
        for (int s = 1; s < 8; s <<= 1) {
            v0 += __shfl_xor(v0, s);
            v1 += __shfl_xor(v1, s);
            v2 += __shfl_xor(v2, s);
            v3 += __shfl_xor(v3, s);
        }
        if (((lane & 7) == 0) && q < 2) {
            const int p = (blockIdx.x * BLOCK + ev) >> 3;
            *(float4*)(out + p * 8 + q * 4) = make_float4(v0, v1, v2, v3);
        }
        __threadfence_block();   // h-row reuse ordering for next g
    }
}

extern "C" void kernel_launch(void* const* d_in, const int* in_sizes, int n_in,
                              void* d_out, int out_size, void* d_ws, size_t ws_size,
                              hipStream_t stream) {
    const float*  xyz = (const float*)d_in[0];
    const float2* tbl = (const float2*)d_in[1];
    const float*  W0  = (const float*)d_in[2];
    const float*  W1  = (const float*)d_in[3];
    const float*  W2  = (const float*)d_in[4];
    const int*    bnd = (const int*)d_in[5];
    float* out = (float*)d_out;

    const int npts  = in_sizes[0] / 3;
    const int total = npts * 8;
    const int grid  = total / BLOCK;

    hipLaunchKernelGGL(prep_w, dim3(14), dim3(64), 0, stream,
                       W0, W1, W2, (uint4*)d_ws);
    hipLaunchKernelGGL(ngp_mfma, dim3(grid), dim3(BLOCK), 0, stream,
                       xyz, tbl, bnd, (const unsigned*)d_ws, out, npts);
}

// Round 6
// 377.133 us; speedup vs baseline: 2.1896x; 1.0166x over previous
//
#include <hip/hip_runtime.h>

// Instant-NGP hash encode (16 levels, F=2) + 32->64->64->8 MLP via MFMA,
// outer trilinear over 8 corners of a 512^3 grid.
//
// R3: MLP on mfma_f32_16x16x32_bf16, transposed D[out][eval].
// R4/R5: spill elimination (launch_bounds 4, single-bf16 weights): 292us.
// R6: LANE-LOCAL layer transitions. Lane (q,col) exits a layer holding D rows
//     {mt*16+q*4+r}; feeding its own packed dwords back as the next B-frag
//     puts h[pi(k)] at HW k-slot q*8+j for a fixed permutation pi, which is
//     baked into W1/W2's K-ordering in prep_w (pi cancels exactly).
//     => no LDS h-region, no fences, no cross-lane ops between layers.
//     LDS 15360->10752 B; MLP dependent chain ~2x shorter.

typedef __attribute__((ext_vector_type(8))) short short8_t;
typedef __attribute__((ext_vector_type(4))) float f32x4;

static constexpr unsigned kT    = 1u << 19;
static constexpr unsigned kMask = kT - 1u;
static constexpr unsigned cP1   = 2654435761u;
static constexpr unsigned cP2   = 805459861u;
static constexpr int      BLOCK = 128;

static __device__ __forceinline__ unsigned bf16_rn(float x) {
    unsigned u = __float_as_uint(x);
    return (u + 0x7fffu + ((u >> 16) & 1u)) >> 16;   // round-to-nearest-even
}

static __device__ __forceinline__ f32x4 mfma16(short8_t a, short8_t b, f32x4 c) {
    return __builtin_amdgcn_mfma_f32_16x16x32_bf16(a, b, c, 0, 0, 0);
}

// ---- weight pre-swizzle: A-frag order, bf16 RNE, 14 tiles x 64 lanes x 16B.
// tiles: 0..3 = W0 (mt = t, K identity); 4..11 = W1 (mt=(t-4)>>1, kt=(t-4)&1);
//        12..13 = W2 (kt = t-12, cols m>=8 zeroed).
// For W1/W2 the K index is permuted by pi to match the lane-local D->B feed:
//   B slot j of lane q carries h[pi] with pi = q*4+j (j<4), 16+q*4+(j-4) (j>=4)
//   (+ kt*32), because lane q's packed D dwords are rows {mt*16+q*4+0..3}.
__global__ void prep_w(const float* __restrict__ W0, const float* __restrict__ W1,
                       const float* __restrict__ W2, uint4* __restrict__ ws)
{
    const int t = blockIdx.x, lane = threadIdx.x;
    const int n = lane & 15, q = lane >> 4;
    unsigned hi[4];
    #pragma unroll
    for (int d = 0; d < 4; ++d) {
        unsigned h2[2];
        #pragma unroll
        for (int s = 0; s < 2; ++s) {
            const int j = d * 2 + s;
            float v;
            if (t < 4) {
                v = W0[(q * 8 + j) * 64 + t * 16 + n];
            } else {
                const int kp = (j < 4) ? (q * 4 + j) : (16 + q * 4 + (j - 4));
                if (t < 12) v = W1[(((t - 4) & 1) * 32 + kp) * 64 + ((t - 4) >> 1) * 16 + n];
                else        v = (n < 8) ? W2[((t - 12) * 32 + kp) * 8 + n] : 0.0f;
            }
            h2[s] = bf16_rn(v);
        }
        hi[d] = h2[0] | (h2[1] << 16);
    }
    ws[t * 64 + lane] = make_uint4(hi[0], hi[1], hi[2], hi[3]);
}

__global__ __launch_bounds__(BLOCK, 4)
void ngp_mfma(const float*  __restrict__ xyz,
              const float2* __restrict__ tbl,
              const int*    __restrict__ boundp,
              const unsigned* __restrict__ wsw,
              float*        __restrict__ out,
              int npts)
{
    // LDS dwords: x [0,2560) eval stride 20dw (80B); wb [2560,2688).
    __shared__ __align__(16) unsigned lds[2688];
    const int tid  = threadIdx.x;
    const int lane = tid & 63;
    const int wv   = tid >> 6;

    // ================= encode (identical numerics to R2) =================
    const int ge = blockIdx.x * BLOCK + tid;
    const int pt = ge >> 3;
    const int b  = ge & 7;

    const float bnd = (float)boundp[0];
    const float sc  = 0.5f / bnd;

    const float pxv = xyz[pt * 3 + 0];
    const float pyv = xyz[pt * 3 + 1];
    const float pzv = xyz[pt * 3 + 2];

    const float cxf = (pxv + bnd) * sc * 512.0f;
    const float cyf = (pyv + bnd) * sc * 512.0f;
    const float czf = (pzv + bnd) * sc * 512.0f;

    const float c0x = fminf(fmaxf(floorf(cxf), 0.0f), 511.0f);
    const float c0y = fminf(fmaxf(floorf(cyf), 0.0f), 511.0f);
    const float c0z = fminf(fmaxf(floorf(czf), 0.0f), 511.0f);
    const float frx = cxf - c0x;
    const float fry = cyf - c0y;
    const float frz = czf - c0z;

    const unsigned kx = (unsigned)c0x + (unsigned)(b & 1);
    const unsigned ky = (unsigned)c0y + (unsigned)((b >> 1) & 1);
    const unsigned kz = (unsigned)c0z + (unsigned)((b >> 2) & 1);

    const float wb = ((b & 1) ? frx : 1.0f - frx)
                   * ((b & 2) ? fry : 1.0f - fry)
                   * ((b & 4) ? frz : 1.0f - frz);

    // fine levels (l=5..15): frac==0, single gather
    const unsigned kyp = ky * cP1;
    const unsigned kzp = kz * cP2;
    float2 gf[11];
    #pragma unroll
    for (int l = 5; l < 16; ++l) {
        const int s = l - 5;
        const unsigned idx = ((kx << s) ^ (kyp << s) ^ (kzp << s)) & kMask;
        gf[l - 5] = tbl[(size_t)l * kT + idx];
    }

    // hashed coarse (l=3,4): prefetch 16 gathers
    float2 gH[2][8];
    #pragma unroll
    for (int l = 3; l < 5; ++l) {
        const int d = 5 - l;
        const unsigned qx = kx >> d, qy = ky >> d, qz = kz >> d;
        const unsigned hy0 = qy * cP1, hy1 = hy0 + cP1;
        const unsigned hz0 = qz * cP2, hz1 = hz0 + cP2;
        const unsigned x1u = qx + 1u;
        const float2* __restrict__ base = tbl + (size_t)l * kT;
        gH[l - 3][0] = base[(qx  ^ hy0 ^ hz0) & kMask];
        gH[l - 3][1] = base[(x1u ^ hy0 ^ hz0) & kMask];
        gH[l - 3][2] = base[(qx  ^ hy1 ^ hz0) & kMask];
        gH[l - 3][3] = base[(x1u ^ hy1 ^ hz0) & kMask];
        gH[l - 3][4] = base[(qx  ^ hy0 ^ hz1) & kMask];
        gH[l - 3][5] = base[(x1u ^ hy0 ^ hz1) & kMask];
        gH[l - 3][6] = base[(qx  ^ hy1 ^ hz1) & kMask];
        gH[l - 3][7] = base[(x1u ^ hy1 ^ hz1) & kMask];
    }

    float2 gc[5];
    #pragma unroll
    for (int l = 0; l < 5; ++l) {
        const int d = 5 - l;
        const unsigned m = (1u << d) - 1u;
        const float inv = 1.0f / (float)(1 << d);
        const unsigned qx = kx >> d, qy = ky >> d, qz = kz >> d;
        const float fx = (float)(kx & m) * inv;
        const float fy = (float)(ky & m) * inv;
        const float fz = (float)(kz & m) * inv;
        float2 g0, g1, g2, g3, g4, g5, g6, g7;
        if (l < 3) {                     // dense, clamp to res
            const unsigned res = 16u << l;
            const unsigned R = res + 1u, R2 = R * R;
            const unsigned x0 = (qx < res ? qx : res);
            const unsigned x1 = (qx + 1u < res ? qx + 1u : res);
            const unsigned y0 = (qy < res ? qy : res) * R;
            const unsigned y1 = (qy + 1u < res ? qy + 1u : res) * R;
            const unsigned z0 = (qz < res ? qz : res) * R2;
            const unsigned z1 = (qz + 1u < res ? qz + 1u : res) * R2;
            const float2* __restrict__ base = tbl + (size_t)l * kT;
            g0 = base[x0 + y0 + z0]; g1 = base[x1 + y0 + z0];
            g2 = base[x0 + y1 + z0]; g3 = base[x1 + y1 + z0];
            g4 = base[x0 + y0 + z1]; g5 = base[x1 + y0 + z1];
            g6 = base[x0 + y1 + z1]; g7 = base[x1 + y1 + z1];
        } else {
            g0 = gH[l - 3][0]; g1 = gH[l - 3][1]; g2 = gH[l - 3][2]; g3 = gH[l - 3][3];
            g4 = gH[l - 3][4]; g5 = gH[l - 3][5]; g6 = gH[l - 3][6]; g7 = gH[l - 3][7];
        }
        const float wx1 = fx, wx0 = 1.0f - fx;
        const float wy1 = fy, wy0 = 1.0f - fy;
        const float wz1 = fz, wz0 = 1.0f - fz;
        const float w00 = wx0 * wy0, w10 = wx1 * wy0, w01 = wx0 * wy1, w11 = wx1 * wy1;
        const float a0 = w00 * wz0, a1 = w10 * wz0, a2 = w01 * wz0, a3 = w11 * wz0;
        const float a4 = w00 * wz1, a5 = w10 * wz1, a6 = w01 * wz1, a7 = w11 * wz1;
        float vx = a0 * g0.x + a1 * g1.x + a2 * g2.x + a3 * g3.x
                 + a4 * g4.x + a5 * g5.x + a6 * g6.x + a7 * g7.x;
        float vy = a0 * g0.y + a1 * g1.y + a2 * g2.y + a3 * g3.y
                 + a4 * g4.y + a5 * g5.y + a6 * g6.y + a7 * g7.y;
        gc[l] = make_float2(vx, vy);
    }

    // pack features: dword l = (bf16(f_{2l}), bf16(f_{2l+1}))
    unsigned xd[16];
    #pragma unroll
    for (int l = 0; l < 16; ++l) {
        const float2 v = (l < 5) ? gc[l] : gf[l - 5];
        xd[l] = bf16_rn(v.x) | (bf16_rn(v.y) << 16);
    }
    uint4* xr = (uint4*)(lds + tid * 20);
    xr[0] = make_uint4(xd[0],  xd[1],  xd[2],  xd[3]);
    xr[1] = make_uint4(xd[4],  xd[5],  xd[6],  xd[7]);
    xr[2] = make_uint4(xd[8],  xd[9],  xd[10], xd[11]);
    xr[3] = make_uint4(xd[12], xd[13], xd[14], xd[15]);
    lds[2560 + tid] = __float_as_uint(wb);
    __threadfence_block();   // x/wb visible to all lanes of this wave

    // ===== weight fragments (compiler may keep in regs or re-read L1) =====
    const short8_t* wf = (const short8_t*)wsw;
    short8_t w[14];
    #pragma unroll
    for (int t = 0; t < 14; ++t) w[t] = wf[t * 64 + lane];

    // ================= MLP (transposed MFMA, lane-local transitions) ======
    const int col = lane & 15;          // = eval within group = MFMA col
    const int q   = lane >> 4;
    const f32x4 zero = {0.0f, 0.0f, 0.0f, 0.0f};

    #pragma unroll 1
    for (int g = 0; g < 4; ++g) {
        const int ev = wv * 64 + g * 16 + col;
        const short8_t xb = *(const short8_t*)(lds + ev * 20 + q * 4);

        unsigned hp0[4], hp1[4];
        // layer 1: physical rows mt*16+q*4+r, eval col
        #pragma unroll
        for (int mt = 0; mt < 4; ++mt) {
            f32x4 a = mfma16(w[mt], xb, zero);
            hp0[mt] = bf16_rn(fmaxf(a[0], 0.0f)) | (bf16_rn(fmaxf(a[1], 0.0f)) << 16);
            hp1[mt] = bf16_rn(fmaxf(a[2], 0.0f)) | (bf16_rn(fmaxf(a[3], 0.0f)) << 16);
        }
        // lane-local B-frags (pi baked into W1's K-order in prep_w)
        uint4 u0 = make_uint4(hp0[0], hp1[0], hp0[1], hp1[1]);
        uint4 u1 = make_uint4(hp0[2], hp1[2], hp0[3], hp1[3]);
        short8_t bk0 = *(short8_t*)&u0;
        short8_t bk1 = *(short8_t*)&u1;

        // layer 2
        #pragma unroll
        for (int mt = 0; mt < 4; ++mt) {
            f32x4 a = mfma16(w[4 + mt * 2], bk0, zero);
            a = mfma16(w[5 + mt * 2], bk1, a);
            hp0[mt] = bf16_rn(fmaxf(a[0], 0.0f)) | (bf16_rn(fmaxf(a[1], 0.0f)) << 16);
            hp1[mt] = bf16_rn(fmaxf(a[2], 0.0f)) | (bf16_rn(fmaxf(a[3], 0.0f)) << 16);
        }
        u0 = make_uint4(hp0[0], hp1[0], hp0[1], hp1[1]);
        u1 = make_uint4(hp0[2], hp1[2], hp0[3], hp1[3]);
        bk0 = *(short8_t*)&u0;
        bk1 = *(short8_t*)&u1;

        // layer 3: out rows q*4+r (only q<2 real; W2 cols >=8 zero-padded)
        f32x4 a3 = mfma16(w[12], bk0, zero);
        a3 = mfma16(w[13], bk1, a3);

        // weight by wb and reduce over the 8 corners (eval low 3 bits)
        const float wbv = __uint_as_float(lds[2560 + ev]);
        float v0 = wbv * a3[0], v1 = wbv * a3[1], v2 = wbv * a3[2], v3 = wbv * a3[3];
        #pragma unroll
        for (int s = 1; s < 8; s <<= 1) {
            v0 += __shfl_xor(v0, s);
            v1 += __shfl_xor(v1, s);
            v2 += __shfl_xor(v2, s);
            v3 += __shfl_xor(v3, s);
        }
        if (((lane & 7) == 0) && q < 2) {
            const int p = (blockIdx.x * BLOCK + ev) >> 3;
            *(float4*)(out + p * 8 + q * 4) = make_float4(v0, v1, v2, v3);
        }
    }
}

extern "C" void kernel_launch(void* const* d_in, const int* in_sizes, int n_in,
                              void* d_out, int out_size, void* d_ws, size_t ws_size,
                              hipStream_t stream) {
    const float*  xyz = (const float*)d_in[0];
    const float2* tbl = (const float2*)d_in[1];
    const float*  W0  = (const float*)d_in[2];
    const float*  W1  = (const float*)d_in[3];
    const float*  W2  = (const float*)d_in[4];
    const int*    bnd = (const int*)d_in[5];
    float* out = (float*)d_out;

    const int npts  = in_sizes[0] / 3;
    const int total = npts * 8;
    const int grid  = total / BLOCK;

    hipLaunchKernelGGL(prep_w, dim3(14), dim3(64), 0, stream,
                       W0, W1, W2, (uint4*)d_ws);
    hipLaunchKernelGGL(ngp_mfma, dim3(grid), dim3(BLOCK), 0, stream,
                       xyz, tbl, bnd, (const unsigned*)d_ws, out, npts);
}

// Round 8
// 374.486 us; speedup vs baseline: 2.2051x; 1.0071x over previous
//
#include <hip/hip_runtime.h>

// Instant-NGP hash encode (16 levels, F=2) + 32->64->64->8 MLP via MFMA,
// outer trilinear over 8 corners of a 512^3 grid.
//
// R3: MLP on mfma_f32_16x16x32_bf16, transposed D[out][eval].
// R4/R5: spill elimination (launch_bounds(128,4), single-bf16 weights).
// R6: lane-local layer transitions (pi baked into W1/W2 K-order). 285us.
// R7 FAILED (replay divergence) with unroll-2 + relaxed bounds: reverted to
//     R6-proven scheduling; fence upgraded to __syncthreads (barrier+fence).
// R8: weight tiles staged in LDS once per block (R6's VGPR=52 shows the
//     compiler re-loaded 14 frags from thrashed L1/L2 inside every g-iter,
//     ~200cyc VMEM in the MFMA chain). Weight reads now ds_read_b128 /
//     LICM-hoisted; wb via shuffle (no LDS slot); x stride 20->16.
//     LDS 8192(x)+14336(w)=22528 B -> 7 blocks/CU (= R6 observed residency).

typedef __attribute__((ext_vector_type(8))) short short8_t;
typedef __attribute__((ext_vector_type(4))) float f32x4;

static constexpr unsigned kT    = 1u << 19;
static constexpr unsigned kMask = kT - 1u;
static constexpr unsigned cP1   = 2654435761u;
static constexpr unsigned cP2   = 805459861u;
static constexpr int      BLOCK = 128;
static constexpr int      WOFF  = 2048;    // LDS dword offset of weight block

static __device__ __forceinline__ unsigned bf16_rn(float x) {
    unsigned u = __float_as_uint(x);
    return (u + 0x7fffu + ((u >> 16) & 1u)) >> 16;   // round-to-nearest-even
}

static __device__ __forceinline__ f32x4 mfma16(short8_t a, short8_t b, f32x4 c) {
    return __builtin_amdgcn_mfma_f32_16x16x32_bf16(a, b, c, 0, 0, 0);
}

// ---- weight pre-swizzle: A-frag order, bf16 RNE, 14 tiles x 64 lanes x 16B.
// tiles: 0..3 = W0 (mt = t, K identity); 4..11 = W1 (mt=(t-4)>>1, kt=(t-4)&1);
//        12..13 = W2 (kt = t-12, cols m>=8 zeroed).
// For W1/W2 the K index is permuted by pi to match the lane-local D->B feed:
//   B slot j of lane q carries h[pi] with pi = q*4+j (j<4), 16+q*4+(j-4) (j>=4)
//   (+ kt*32), because lane q's packed D dwords are rows {mt*16+q*4+0..3}.
__global__ void prep_w(const float* __restrict__ W0, const float* __restrict__ W1,
                       const float* __restrict__ W2, uint4* __restrict__ ws)
{
    const int t = blockIdx.x, lane = threadIdx.x;
    const int n = lane & 15, q = lane >> 4;
    unsigned hi[4];
    #pragma unroll
    for (int d = 0; d < 4; ++d) {
        unsigned h2[2];
        #pragma unroll
        for (int s = 0; s < 2; ++s) {
            const int j = d * 2 + s;
            float v;
            if (t < 4) {
                v = W0[(q * 8 + j) * 64 + t * 16 + n];
            } else {
                const int kp = (j < 4) ? (q * 4 + j) : (16 + q * 4 + (j - 4));
                if (t < 12) v = W1[(((t - 4) & 1) * 32 + kp) * 64 + ((t - 4) >> 1) * 16 + n];
                else        v = (n < 8) ? W2[((t - 12) * 32 + kp) * 8 + n] : 0.0f;
            }
            h2[s] = bf16_rn(v);
        }
        hi[d] = h2[0] | (h2[1] << 16);
    }
    ws[t * 64 + lane] = make_uint4(hi[0], hi[1], hi[2], hi[3]);
}

__global__ __launch_bounds__(BLOCK, 4)
void ngp_mfma(const float*  __restrict__ xyz,
              const float2* __restrict__ tbl,
              const int*    __restrict__ boundp,
              const unsigned* __restrict__ wsw,
              float*        __restrict__ out,
              int npts)
{
    // LDS dwords: x [0,2048) eval stride 16dw (64B); weights [2048,5632).
    __shared__ __align__(16) unsigned lds[5632];
    const int tid  = threadIdx.x;
    const int lane = tid & 63;
    const int wv   = tid >> 6;

    // ---- stage weight block (14336 B) into LDS, coalesced ----
    {
        const uint4* __restrict__ wsrc = (const uint4*)wsw;
        uint4* wdst = (uint4*)(lds + WOFF);
        #pragma unroll
        for (int k = 0; k < 7; ++k) wdst[tid + k * 128] = wsrc[tid + k * 128];
    }

    // ================= encode (identical numerics to R2) =================
    const int ge = blockIdx.x * BLOCK + tid;
    const int pt = ge >> 3;
    const int b  = ge & 7;

    const float bnd = (float)boundp[0];
    const float sc  = 0.5f / bnd;

    const float pxv = xyz[pt * 3 + 0];
    const float pyv = xyz[pt * 3 + 1];
    const float pzv = xyz[pt * 3 + 2];

    const float cxf = (pxv + bnd) * sc * 512.0f;
    const float cyf = (pyv + bnd) * sc * 512.0f;
    const float czf = (pzv + bnd) * sc * 512.0f;

    const float c0x = fminf(fmaxf(floorf(cxf), 0.0f), 511.0f);
    const float c0y = fminf(fmaxf(floorf(cyf), 0.0f), 511.0f);
    const float c0z = fminf(fmaxf(floorf(czf), 0.0f), 511.0f);
    const float frx = cxf - c0x;
    const float fry = cyf - c0y;
    const float frz = czf - c0z;

    const unsigned kx = (unsigned)c0x + (unsigned)(b & 1);
    const unsigned ky = (unsigned)c0y + (unsigned)((b >> 1) & 1);
    const unsigned kz = (unsigned)c0z + (unsigned)((b >> 2) & 1);

    const float wb = ((b & 1) ? frx : 1.0f - frx)
                   * ((b & 2) ? fry : 1.0f - fry)
                   * ((b & 4) ? frz : 1.0f - frz);

    // fine levels (l=5..15): frac==0, single gather
    const unsigned kyp = ky * cP1;
    const unsigned kzp = kz * cP2;
    float2 gf[11];
    #pragma unroll
    for (int l = 5; l < 16; ++l) {
        const int s = l - 5;
        const unsigned idx = ((kx << s) ^ (kyp << s) ^ (kzp << s)) & kMask;
        gf[l - 5] = tbl[(size_t)l * kT + idx];
    }

    // hashed coarse (l=3,4): prefetch 16 gathers
    float2 gH[2][8];
    #pragma unroll
    for (int l = 3; l < 5; ++l) {
        const int d = 5 - l;
        const unsigned qx = kx >> d, qy = ky >> d, qz = kz >> d;
        const unsigned hy0 = qy * cP1, hy1 = hy0 + cP1;
        const unsigned hz0 = qz * cP2, hz1 = hz0 + cP2;
        const unsigned x1u = qx + 1u;
        const float2* __restrict__ base = tbl + (size_t)l * kT;
        gH[l - 3][0] = base[(qx  ^ hy0 ^ hz0) & kMask];
        gH[l - 3][1] = base[(x1u ^ hy0 ^ hz0) & kMask];
        gH[l - 3][2] = base[(qx  ^ hy1 ^ hz0) & kMask];
        gH[l - 3][3] = base[(x1u ^ hy1 ^ hz0) & kMask];
        gH[l - 3][4] = base[(qx  ^ hy0 ^ hz1) & kMask];
        gH[l - 3][5] = base[(x1u ^ hy0 ^ hz1) & kMask];
        gH[l - 3][6] = base[(qx  ^ hy1 ^ hz1) & kMask];
        gH[l - 3][7] = base[(x1u ^ hy1 ^ hz1) & kMask];
    }

    float2 gc[5];
    #pragma unroll
    for (int l = 0; l < 5; ++l) {
        const int d = 5 - l;
        const unsigned m = (1u << d) - 1u;
        const float inv = 1.0f / (float)(1 << d);
        const unsigned qx = kx >> d, qy = ky >> d, qz = kz >> d;
        const float fx = (float)(kx & m) * inv;
        const float fy = (float)(ky & m) * inv;
        const float fz = (float)(kz & m) * inv;
        float2 g0, g1, g2, g3, g4, g5, g6, g7;
        if (l < 3) {                     // dense, clamp to res
            const unsigned res = 16u << l;
            const unsigned R = res + 1u, R2 = R * R;
            const unsigned x0 = (qx < res ? qx : res);
            const unsigned x1 = (qx + 1u < res ? qx + 1u : res);
            const unsigned y0 = (qy < res ? qy : res) * R;
            const unsigned y1 = (qy + 1u < res ? qy + 1u : res) * R;
            const unsigned z0 = (qz < res ? qz : res) * R2;
            const unsigned z1 = (qz + 1u < res ? qz + 1u : res) * R2;
            const float2* __restrict__ base = tbl + (size_t)l * kT;
            g0 = base[x0 + y0 + z0]; g1 = base[x1 + y0 + z0];
            g2 = base[x0 + y1 + z0]; g3 = base[x1 + y1 + z0];
            g4 = base[x0 + y0 + z1]; g5 = base[x1 + y0 + z1];
            g6 = base[x0 + y1 + z1]; g7 = base[x1 + y1 + z1];
        } else {
            g0 = gH[l - 3][0]; g1 = gH[l - 3][1]; g2 = gH[l - 3][2]; g3 = gH[l - 3][3];
            g4 = gH[l - 3][4]; g5 = gH[l - 3][5]; g6 = gH[l - 3][6]; g7 = gH[l - 3][7];
        }
        const float wx1 = fx, wx0 = 1.0f - fx;
        const float wy1 = fy, wy0 = 1.0f - fy;
        const float wz1 = fz, wz0 = 1.0f - fz;
        const float w00 = wx0 * wy0, w10 = wx1 * wy0, w01 = wx0 * wy1, w11 = wx1 * wy1;
        const float a0 = w00 * wz0, a1 = w10 * wz0, a2 = w01 * wz0, a3 = w11 * wz0;
        const float a4 = w00 * wz1, a5 = w10 * wz1, a6 = w01 * wz1, a7 = w11 * wz1;
        float vx = a0 * g0.x + a1 * g1.x + a2 * g2.x + a3 * g3.x
                 + a4 * g4.x + a5 * g5.x + a6 * g6.x + a7 * g7.x;
        float vy = a0 * g0.y + a1 * g1.y + a2 * g2.y + a3 * g3.y
                 + a4 * g4.y + a5 * g5.y + a6 * g6.y + a7 * g7.y;
        gc[l] = make_float2(vx, vy);
    }

    // pack features: dword l = (bf16(f_{2l}), bf16(f_{2l+1}))
    unsigned xd[16];
    #pragma unroll
    for (int l = 0; l < 16; ++l) {
        const float2 v = (l < 5) ? gc[l] : gf[l - 5];
        xd[l] = bf16_rn(v.x) | (bf16_rn(v.y) << 16);
    }
    uint4* xr = (uint4*)(lds + tid * 16);
    xr[0] = make_uint4(xd[0],  xd[1],  xd[2],  xd[3]);
    xr[1] = make_uint4(xd[4],  xd[5],  xd[6],  xd[7]);
    xr[2] = make_uint4(xd[8],  xd[9],  xd[10], xd[11]);
    xr[3] = make_uint4(xd[12], xd[13], xd[14], xd[15]);

    __syncthreads();   // x + staged weights visible block-wide (barrier+fence)

    // ================= MLP (transposed MFMA, lane-local transitions) ======
    const short8_t* __restrict__ wl = (const short8_t*)(lds + WOFF);
    const int col = lane & 15;          // = eval within group = MFMA col
    const int q   = lane >> 4;
    const f32x4 zero = {0.0f, 0.0f, 0.0f, 0.0f};

    #pragma unroll 1
    for (int g = 0; g < 4; ++g) {
        const int ev = wv * 64 + g * 16 + col;
        const short8_t xb = *(const short8_t*)(lds + ev * 16 + q * 4);
        const float wbv = __shfl(wb, g * 16 + col, 64);   // wb of the source lane

        unsigned hp0[4], hp1[4];
        // layer 1: physical rows mt*16+q*4+r, eval col
        #pragma unroll
        for (int mt = 0; mt < 4; ++mt) {
            f32x4 a = mfma16(wl[mt * 64 + lane], xb, zero);
            hp0[mt] = bf16_rn(fmaxf(a[0], 0.0f)) | (bf16_rn(fmaxf(a[1], 0.0f)) << 16);
            hp1[mt] = bf16_rn(fmaxf(a[2], 0.0f)) | (bf16_rn(fmaxf(a[3], 0.0f)) << 16);
        }
        // lane-local B-frags (pi baked into W1's K-order in prep_w)
        uint4 u0 = make_uint4(hp0[0], hp1[0], hp0[1], hp1[1]);
        uint4 u1 = make_uint4(hp0[2], hp1[2], hp0[3], hp1[3]);
        short8_t bk0 = *(short8_t*)&u0;
        short8_t bk1 = *(short8_t*)&u1;

        // layer 2
        #pragma unroll
        for (int mt = 0; mt < 4; ++mt) {
            f32x4 a = mfma16(wl[(4 + mt * 2) * 64 + lane], bk0, zero);
            a = mfma16(wl[(5 + mt * 2) * 64 + lane], bk1, a);
            hp0[mt] = bf16_rn(fmaxf(a[0], 0.0f)) | (bf16_rn(fmaxf(a[1], 0.0f)) << 16);
            hp1[mt] = bf16_rn(fmaxf(a[2], 0.0f)) | (bf16_rn(fmaxf(a[3], 0.0f)) << 16);
        }
        u0 = make_uint4(hp0[0], hp1[0], hp0[1], hp1[1]);
        u1 = make_uint4(hp0[2], hp1[2], hp0[3], hp1[3]);
        bk0 = *(short8_t*)&u0;
        bk1 = *(short8_t*)&u1;

        // layer 3: out rows q*4+r (only q<2 real; W2 cols >=8 zero-padded)
        f32x4 a3 = mfma16(wl[12 * 64 + lane], bk0, zero);
        a3 = mfma16(wl[13 * 64 + lane], bk1, a3);

        // weight by wb and reduce over the 8 corners (eval low 3 bits)
        float v0 = wbv * a3[0], v1 = wbv * a3[1], v2 = wbv * a3[2], v3 = wbv * a3[3];
        #pragma unroll
        for (int s = 1; s < 8; s <<= 1) {
            v0 += __shfl_xor(v0, s);
            v1 += __shfl_xor(v1, s);
            v2 += __shfl_xor(v2, s);
            v3 += __shfl_xor(v3, s);
        }
        if (((lane & 7) == 0) && q < 2) {
            const int p = (blockIdx.x * BLOCK + ev) >> 3;
            *(float4*)(out + p * 8 + q * 4) = make_float4(v0, v1, v2, v3);
        }
    }
}

extern "C" void kernel_launch(void* const* d_in, const int* in_sizes, int n_in,
                              void* d_out, int out_size, void* d_ws, size_t ws_size,
                              hipStream_t stream) {
    const float*  xyz = (const float*)d_in[0];
    const float2* tbl = (const float2*)d_in[1];
    const float*  W0  = (const float*)d_in[2];
    const float*  W1  = (const float*)d_in[3];
    const float*  W2  = (const float*)d_in[4];
    const int*    bnd = (const int*)d_in[5];
    float* out = (float*)d_out;

    const int npts  = in_sizes[0] / 3;
    const int total = npts * 8;
    const int grid  = total / BLOCK;

    hipLaunchKernelGGL(prep_w, dim3(14), dim3(64), 0, stream,
                       W0, W1, W2, (uint4*)d_ws);
    hipLaunchKernelGGL(ngp_mfma, dim3(grid), dim3(BLOCK), 0, stream,
                       xyz, tbl, bnd, (const unsigned*)d_ws, out, npts);
}

// Round 9
// 373.810 us; speedup vs baseline: 2.2091x; 1.0018x over previous
//
#include <hip/hip_runtime.h>

// Instant-NGP hash encode (16 levels, F=2) + 32->64->64->8 MLP via MFMA,
// outer trilinear over 8 corners of a 512^3 grid.
//
// R3: MLP on mfma_f32_16x16x32_bf16, transposed D[out][eval].
// R4/R5: spill elimination (launch_bounds, single-bf16 weights).
// R6: lane-local layer transitions (pi baked into W1/W2 K-order). 285us.
// R7 FAILED (replay divergence, unroll-2): reverted; __syncthreads kept.
// R8: weights staged in LDS once per block. 281us, but LDS-occupancy-capped
//     (22528 B -> 7 blocks x 2 waves = 43.75% cap, measured 38%).
// R9: BLOCK 128->256 — four waves share one weight block. LDS/block =
//     16K(x) + 14K(w) = 30720 B -> 5 blocks x 4 waves = 20 waves/CU (62.5%
//     cap). More outstanding gather bursts per CU to hide L2-miss latency.
//     Structure otherwise byte-identical to R8 (proven replay-stable).

typedef __attribute__((ext_vector_type(8))) short short8_t;
typedef __attribute__((ext_vector_type(4))) float f32x4;

static constexpr unsigned kT    = 1u << 19;
static constexpr unsigned kMask = kT - 1u;
static constexpr unsigned cP1   = 2654435761u;
static constexpr unsigned cP2   = 805459861u;
static constexpr int      BLOCK = 256;
static constexpr int      WOFF  = 4096;    // LDS dword offset of weight block

static __device__ __forceinline__ unsigned bf16_rn(float x) {
    unsigned u = __float_as_uint(x);
    return (u + 0x7fffu + ((u >> 16) & 1u)) >> 16;   // round-to-nearest-even
}

static __device__ __forceinline__ f32x4 mfma16(short8_t a, short8_t b, f32x4 c) {
    return __builtin_amdgcn_mfma_f32_16x16x32_bf16(a, b, c, 0, 0, 0);
}

// ---- weight pre-swizzle: A-frag order, bf16 RNE, 14 tiles x 64 lanes x 16B.
// tiles: 0..3 = W0 (mt = t, K identity); 4..11 = W1 (mt=(t-4)>>1, kt=(t-4)&1);
//        12..13 = W2 (kt = t-12, cols m>=8 zeroed).
// For W1/W2 the K index is permuted by pi to match the lane-local D->B feed:
//   B slot j of lane q carries h[pi] with pi = q*4+j (j<4), 16+q*4+(j-4) (j>=4)
//   (+ kt*32), because lane q's packed D dwords are rows {mt*16+q*4+0..3}.
__global__ void prep_w(const float* __restrict__ W0, const float* __restrict__ W1,
                       const float* __restrict__ W2, uint4* __restrict__ ws)
{
    const int t = blockIdx.x, lane = threadIdx.x;
    const int n = lane & 15, q = lane >> 4;
    unsigned hi[4];
    #pragma unroll
    for (int d = 0; d < 4; ++d) {
        unsigned h2[2];
        #pragma unroll
        for (int s = 0; s < 2; ++s) {
            const int j = d * 2 + s;
            float v;
            if (t < 4) {
                v = W0[(q * 8 + j) * 64 + t * 16 + n];
            } else {
                const int kp = (j < 4) ? (q * 4 + j) : (16 + q * 4 + (j - 4));
                if (t < 12) v = W1[(((t - 4) & 1) * 32 + kp) * 64 + ((t - 4) >> 1) * 16 + n];
                else        v = (n < 8) ? W2[((t - 12) * 32 + kp) * 8 + n] : 0.0f;
            }
            h2[s] = bf16_rn(v);
        }
        hi[d] = h2[0] | (h2[1] << 16);
    }
    ws[t * 64 + lane] = make_uint4(hi[0], hi[1], hi[2], hi[3]);
}

__global__ __launch_bounds__(BLOCK, 5)
void ngp_mfma(const float*  __restrict__ xyz,
              const float2* __restrict__ tbl,
              const int*    __restrict__ boundp,
              const unsigned* __restrict__ wsw,
              float*        __restrict__ out,
              int npts)
{
    // LDS dwords: x [0,4096) eval stride 16dw (64B); weights [4096,7680).
    __shared__ __align__(16) unsigned lds[7680];
    const int tid  = threadIdx.x;
    const int lane = tid & 63;
    const int wv   = tid >> 6;

    // ---- stage weight block (14336 B = 896 uint4) into LDS, coalesced ----
    {
        const uint4* __restrict__ wsrc = (const uint4*)wsw;
        uint4* wdst = (uint4*)(lds + WOFF);
        #pragma unroll
        for (int k = 0; k < 4; ++k) {
            const int i = tid + k * 256;
            if (i < 896) wdst[i] = wsrc[i];
        }
    }

    // ================= encode (identical numerics to R2) =================
    const int ge = blockIdx.x * BLOCK + tid;
    const int pt = ge >> 3;
    const int b  = ge & 7;

    const float bnd = (float)boundp[0];
    const float sc  = 0.5f / bnd;

    const float pxv = xyz[pt * 3 + 0];
    const float pyv = xyz[pt * 3 + 1];
    const float pzv = xyz[pt * 3 + 2];

    const float cxf = (pxv + bnd) * sc * 512.0f;
    const float cyf = (pyv + bnd) * sc * 512.0f;
    const float czf = (pzv + bnd) * sc * 512.0f;

    const float c0x = fminf(fmaxf(floorf(cxf), 0.0f), 511.0f);
    const float c0y = fminf(fmaxf(floorf(cyf), 0.0f), 511.0f);
    const float c0z = fminf(fmaxf(floorf(czf), 0.0f), 511.0f);
    const float frx = cxf - c0x;
    const float fry = cyf - c0y;
    const float frz = czf - c0z;

    const unsigned kx = (unsigned)c0x + (unsigned)(b & 1);
    const unsigned ky = (unsigned)c0y + (unsigned)((b >> 1) & 1);
    const unsigned kz = (unsigned)c0z + (unsigned)((b >> 2) & 1);

    const float wb = ((b & 1) ? frx : 1.0f - frx)
                   * ((b & 2) ? fry : 1.0f - fry)
                   * ((b & 4) ? frz : 1.0f - frz);

    // fine levels (l=5..15): frac==0, single gather
    const unsigned kyp = ky * cP1;
    const unsigned kzp = kz * cP2;
    float2 gf[11];
    #pragma unroll
    for (int l = 5; l < 16; ++l) {
        const int s = l - 5;
        const unsigned idx = ((kx << s) ^ (kyp << s) ^ (kzp << s)) & kMask;
        gf[l - 5] = tbl[(size_t)l * kT + idx];
    }

    // hashed coarse (l=3,4): prefetch 16 gathers
    float2 gH[2][8];
    #pragma unroll
    for (int l = 3; l < 5; ++l) {
        const int d = 5 - l;
        const unsigned qx = kx >> d, qy = ky >> d, qz = kz >> d;
        const unsigned hy0 = qy * cP1, hy1 = hy0 + cP1;
        const unsigned hz0 = qz * cP2, hz1 = hz0 + cP2;
        const unsigned x1u = qx + 1u;
        const float2* __restrict__ base = tbl + (size_t)l * kT;
        gH[l - 3][0] = base[(qx  ^ hy0 ^ hz0) & kMask];
        gH[l - 3][1] = base[(x1u ^ hy0 ^ hz0) & kMask];
        gH[l - 3][2] = base[(qx  ^ hy1 ^ hz0) & kMask];
        gH[l - 3][3] = base[(x1u ^ hy1 ^ hz0) & kMask];
        gH[l - 3][4] = base[(qx  ^ hy0 ^ hz1) & kMask];
        gH[l - 3][5] = base[(x1u ^ hy0 ^ hz1) & kMask];
        gH[l - 3][6] = base[(qx  ^ hy1 ^ hz1) & kMask];
        gH[l - 3][7] = base[(x1u ^ hy1 ^ hz1) & kMask];
    }

    float2 gc[5];
    #pragma unroll
    for (int l = 0; l < 5; ++l) {
        const int d = 5 - l;
        const unsigned m = (1u << d) - 1u;
        const float inv = 1.0f / (float)(1 << d);
        const unsigned qx = kx >> d, qy = ky >> d, qz = kz >> d;
        const float fx = (float)(kx & m) * inv;
        const float fy = (float)(ky & m) * inv;
        const float fz = (float)(kz & m) * inv;
        float2 g0, g1, g2, g3, g4, g5, g6, g7;
        if (l < 3) {                     // dense, clamp to res
            const unsigned res = 16u << l;
            const unsigned R = res + 1u, R2 = R * R;
            const unsigned x0 = (qx < res ? qx : res);
            const unsigned x1 = (qx + 1u < res ? qx + 1u : res);
            const unsigned y0 = (qy < res ? qy : res) * R;
            const unsigned y1 = (qy + 1u < res ? qy + 1u : res) * R;
            const unsigned z0 = (qz < res ? qz : res) * R2;
            const unsigned z1 = (qz + 1u < res ? qz + 1u : res) * R2;
            const float2* __restrict__ base = tbl + (size_t)l * kT;
            g0 = base[x0 + y0 + z0]; g1 = base[x1 + y0 + z0];
            g2 = base[x0 + y1 + z0]; g3 = base[x1 + y1 + z0];
            g4 = base[x0 + y0 + z1]; g5 = base[x1 + y0 + z1];
            g6 = base[x0 + y1 + z1]; g7 = base[x1 + y1 + z1];
        } else {
            g0 = gH[l - 3][0]; g1 = gH[l - 3][1]; g2 = gH[l - 3][2]; g3 = gH[l - 3][3];
            g4 = gH[l - 3][4]; g5 = gH[l - 3][5]; g6 = gH[l - 3][6]; g7 = gH[l - 3][7];
        }
        const float wx1 = fx, wx0 = 1.0f - fx;
        const float wy1 = fy, wy0 = 1.0f - fy;
        const float wz1 = fz, wz0 = 1.0f - fz;
        const float w00 = wx0 * wy0, w10 = wx1 * wy0, w01 = wx0 * wy1, w11 = wx1 * wy1;
        const float a0 = w00 * wz0, a1 = w10 * wz0, a2 = w01 * wz0, a3 = w11 * wz0;
        const float a4 = w00 * wz1, a5 = w10 * wz1, a6 = w01 * wz1, a7 = w11 * wz1;
        float vx = a0 * g0.x + a1 * g1.x + a2 * g2.x + a3 * g3.x
                 + a4 * g4.x + a5 * g5.x + a6 * g6.x + a7 * g7.x;
        float vy = a0 * g0.y + a1 * g1.y + a2 * g2.y + a3 * g3.y
                 + a4 * g4.y + a5 * g5.y + a6 * g6.y + a7 * g7.y;
        gc[l] = make_float2(vx, vy);
    }

    // pack features: dword l = (bf16(f_{2l}), bf16(f_{2l+1}))
    unsigned xd[16];
    #pragma unroll
    for (int l = 0; l < 16; ++l) {
        const float2 v = (l < 5) ? gc[l] : gf[l - 5];
        xd[l] = bf16_rn(v.x) | (bf16_rn(v.y) << 16);
    }
    uint4* xr = (uint4*)(lds + tid * 16);
    xr[0] = make_uint4(xd[0],  xd[1],  xd[2],  xd[3]);
    xr[1] = make_uint4(xd[4],  xd[5],  xd[6],  xd[7]);
    xr[2] = make_uint4(xd[8],  xd[9],  xd[10], xd[11]);
    xr[3] = make_uint4(xd[12], xd[13], xd[14], xd[15]);

    __syncthreads();   // x + staged weights visible block-wide (barrier+fence)

    // ================= MLP (transposed MFMA, lane-local transitions) ======
    const short8_t* __restrict__ wl = (const short8_t*)(lds + WOFF);
    const int col = lane & 15;          // = eval within group = MFMA col
    const int q   = lane >> 4;
    const f32x4 zero = {0.0f, 0.0f, 0.0f, 0.0f};

    #pragma unroll 1
    for (int g = 0; g < 4; ++g) {
        const int ev = wv * 64 + g * 16 + col;
        const short8_t xb = *(const short8_t*)(lds + ev * 16 + q * 4);
        const float wbv = __shfl(wb, g * 16 + col, 64);   // wb of the source lane

        unsigned hp0[4], hp1[4];
        // layer 1: physical rows mt*16+q*4+r, eval col
        #pragma unroll
        for (int mt = 0; mt < 4; ++mt) {
            f32x4 a = mfma16(wl[mt * 64 + lane], xb, zero);
            hp0[mt] = bf16_rn(fmaxf(a[0], 0.0f)) | (bf16_rn(fmaxf(a[1], 0.0f)) << 16);
            hp1[mt] = bf16_rn(fmaxf(a[2], 0.0f)) | (bf16_rn(fmaxf(a[3], 0.0f)) << 16);
        }
        // lane-local B-frags (pi baked into W1's K-order in prep_w)
        uint4 u0 = make_uint4(hp0[0], hp1[0], hp0[1], hp1[1]);
        uint4 u1 = make_uint4(hp0[2], hp1[2], hp0[3], hp1[3]);
        short8_t bk0 = *(short8_t*)&u0;
        short8_t bk1 = *(short8_t*)&u1;

        // layer 2
        #pragma unroll
        for (int mt = 0; mt < 4; ++mt) {
            f32x4 a = mfma16(wl[(4 + mt * 2) * 64 + lane], bk0, zero);
            a = mfma16(wl[(5 + mt * 2) * 64 + lane], bk1, a);
            hp0[mt] = bf16_rn(fmaxf(a[0], 0.0f)) | (bf16_rn(fmaxf(a[1], 0.0f)) << 16);
            hp1[mt] = bf16_rn(fmaxf(a[2], 0.0f)) | (bf16_rn(fmaxf(a[3], 0.0f)) << 16);
        }
        u0 = make_uint4(hp0[0], hp1[0], hp0[1], hp1[1]);
        u1 = make_uint4(hp0[2], hp1[2], hp0[3], hp1[3]);
        bk0 = *(short8_t*)&u0;
        bk1 = *(short8_t*)&u1;

        // layer 3: out rows q*4+r (only q<2 real; W2 cols >=8 zero-padded)
        f32x4 a3 = mfma16(wl[12 * 64 + lane], bk0, zero);
        a3 = mfma16(wl[13 * 64 + lane], bk1, a3);

        // weight by wb and reduce over the 8 corners (eval low 3 bits)
        float v0 = wbv * a3[0], v1 = wbv * a3[1], v2 = wbv * a3[2], v3 = wbv * a3[3];
        #pragma unroll
        for (int s = 1; s < 8; s <<= 1) {
            v0 += __shfl_xor(v0, s);
            v1 += __shfl_xor(v1, s);
            v2 += __shfl_xor(v2, s);
            v3 += __shfl_xor(v3, s);
        }
        if (((lane & 7) == 0) && q < 2) {
            const int p = (blockIdx.x * BLOCK + ev) >> 3;
            *(float4*)(out + p * 8 + q * 4) = make_float4(v0, v1, v2, v3);
        }
    }
}

extern "C" void kernel_launch(void* const* d_in, const int* in_sizes, int n_in,
                              void* d_out, int out_size, void* d_ws, size_t ws_size,
                              hipStream_t stream) {
    const float*  xyz = (const float*)d_in[0];
    const float2* tbl = (const float2*)d_in[1];
    const float*  W0  = (const float*)d_in[2];
    const float*  W1  = (const float*)d_in[3];
    const float*  W2  = (const float*)d_in[4];
    const int*    bnd = (const int*)d_in[5];
    float* out = (float*)d_out;

    const int npts  = in_sizes[0] / 3;
    const int total = npts * 8;
    const int grid  = total / BLOCK;

    hipLaunchKernelGGL(prep_w, dim3(14), dim3(64), 0, stream,
                       W0, W1, W2, (uint4*)d_ws);
    hipLaunchKernelGGL(ngp_mfma, dim3(grid), dim3(BLOCK), 0, stream,
                       xyz, tbl, bnd, (const unsigned*)d_ws, out, npts);
}

// Round 10
// 351.858 us; speedup vs baseline: 2.3469x; 1.0624x over previous
//
#include <hip/hip_runtime.h>

// Instant-NGP hash encode (16 levels, F=2) + 32->64->64->8 MLP via MFMA,
// outer trilinear over 8 corners of a 512^3 grid.
//
// R3-R6: MFMA MLP, lane-local layer transitions, spill-free. 285us.
// R7 FAILED (replay divergence, unroll-2): reverted; __syncthreads kept.
// R8: weights staged in LDS. R9: BLOCK 256, occupancy 38->55% — dur FLAT at
//     281us => not wave-starved; memory path saturated (FETCH 1.0 GB @ 3.7
//     TB/s L2-fill, constant across R6/R8/R9).
// R10: halve the random-gather line footprint: hashed levels (3..15) of the
//     table pre-converted to packed bf16 in d_ws (52->26 MB random region;
//     L2 hit rate up, FETCH down). Fine levels bit-identical (bf16_rn
//     idempotent vs the existing x-pack quantization); only l=3,4 trilerp
//     corners are quantized (absmax ~6-8e-7, threshold 2.3e-6). Dense
//     levels 0-2 stay fp32 (cache-resident). Guarded by ws_size.

typedef __attribute__((ext_vector_type(8))) short short8_t;
typedef __attribute__((ext_vector_type(4))) float f32x4;

static constexpr unsigned kT    = 1u << 19;
static constexpr unsigned kMask = kT - 1u;
static constexpr unsigned cP1   = 2654435761u;
static constexpr unsigned cP2   = 805459861u;
static constexpr int      BLOCK = 256;
static constexpr int      WOFF  = 4096;    // LDS dword offset of weight block
static constexpr int      TOFF  = 4096;    // d_ws dword offset of bf16 table
static constexpr size_t   WS_NEED = 16384 + (size_t)13 * kT * 4;  // bytes

static __device__ __forceinline__ unsigned bf16_rn(float x) {
    unsigned u = __float_as_uint(x);
    return (u + 0x7fffu + ((u >> 16) & 1u)) >> 16;   // round-to-nearest-even
}

static __device__ __forceinline__ float2 bf2dec(unsigned u) {
    return make_float2(__uint_as_float(u << 16),
                       __uint_as_float(u & 0xffff0000u));
}

static __device__ __forceinline__ f32x4 mfma16(short8_t a, short8_t b, f32x4 c) {
    return __builtin_amdgcn_mfma_f32_16x16x32_bf16(a, b, c, 0, 0, 0);
}

// ---- weight pre-swizzle: A-frag order, bf16 RNE, 14 tiles x 64 lanes x 16B.
// tiles: 0..3 = W0 (mt = t, K identity); 4..11 = W1 (mt=(t-4)>>1, kt=(t-4)&1);
//        12..13 = W2 (kt = t-12, cols m>=8 zeroed).
// W1/W2 K-index permuted by pi to match the lane-local D->B feed.
__global__ void prep_w(const float* __restrict__ W0, const float* __restrict__ W1,
                       const float* __restrict__ W2, uint4* __restrict__ ws)
{
    const int t = blockIdx.x, lane = threadIdx.x;
    const int n = lane & 15, q = lane >> 4;
    unsigned hi[4];
    #pragma unroll
    for (int d = 0; d < 4; ++d) {
        unsigned h2[2];
        #pragma unroll
        for (int s = 0; s < 2; ++s) {
            const int j = d * 2 + s;
            float v;
            if (t < 4) {
                v = W0[(q * 8 + j) * 64 + t * 16 + n];
            } else {
                const int kp = (j < 4) ? (q * 4 + j) : (16 + q * 4 + (j - 4));
                if (t < 12) v = W1[(((t - 4) & 1) * 32 + kp) * 64 + ((t - 4) >> 1) * 16 + n];
                else        v = (n < 8) ? W2[((t - 12) * 32 + kp) * 8 + n] : 0.0f;
            }
            h2[s] = bf16_rn(v);
        }
        hi[d] = h2[0] | (h2[1] << 16);
    }
    ws[t * 64 + lane] = make_uint4(hi[0], hi[1], hi[2], hi[3]);
}

// ---- table convert: levels 3..15 fp32x2 -> packed bf16x2 (one dword/entry)
__global__ void conv_t(const float4* __restrict__ src, uint2* __restrict__ dst)
{
    const int i = blockIdx.x * 256 + threadIdx.x;   // pair of entries
    const float4 v = src[i];
    dst[i] = make_uint2(bf16_rn(v.x) | (bf16_rn(v.y) << 16),
                        bf16_rn(v.z) | (bf16_rn(v.w) << 16));
}

template<bool BT>
__global__ __launch_bounds__(BLOCK, 5)
void ngp_mfma(const float*  __restrict__ xyz,
              const float2* __restrict__ tbl,
              const int*    __restrict__ boundp,
              const unsigned* __restrict__ wsw,
              float*        __restrict__ out,
              int npts)
{
    // LDS dwords: x [0,4096) eval stride 16dw (64B); weights [4096,7680).
    __shared__ __align__(16) unsigned lds[7680];
    const int tid  = threadIdx.x;
    const int lane = tid & 63;
    const int wv   = tid >> 6;

    // ---- stage weight block (14336 B = 896 uint4) into LDS, coalesced ----
    {
        const uint4* __restrict__ wsrc = (const uint4*)wsw;
        uint4* wdst = (uint4*)(lds + WOFF);
        #pragma unroll
        for (int k = 0; k < 4; ++k) {
            const int i = tid + k * 256;
            if (i < 896) wdst[i] = wsrc[i];
        }
    }

    const unsigned* __restrict__ tbx = wsw + TOFF;  // bf16 table, levels 3..15

    // ================= encode =================
    const int ge = blockIdx.x * BLOCK + tid;
    const int pt = ge >> 3;
    const int b  = ge & 7;

    const float bnd = (float)boundp[0];
    const float sc  = 0.5f / bnd;

    const float pxv = xyz[pt * 3 + 0];
    const float pyv = xyz[pt * 3 + 1];
    const float pzv = xyz[pt * 3 + 2];

    const float cxf = (pxv + bnd) * sc * 512.0f;
    const float cyf = (pyv + bnd) * sc * 512.0f;
    const float czf = (pzv + bnd) * sc * 512.0f;

    const float c0x = fminf(fmaxf(floorf(cxf), 0.0f), 511.0f);
    const float c0y = fminf(fmaxf(floorf(cyf), 0.0f), 511.0f);
    const float c0z = fminf(fmaxf(floorf(czf), 0.0f), 511.0f);
    const float frx = cxf - c0x;
    const float fry = cyf - c0y;
    const float frz = czf - c0z;

    const unsigned kx = (unsigned)c0x + (unsigned)(b & 1);
    const unsigned ky = (unsigned)c0y + (unsigned)((b >> 1) & 1);
    const unsigned kz = (unsigned)c0z + (unsigned)((b >> 2) & 1);

    const float wb = ((b & 1) ? frx : 1.0f - frx)
                   * ((b & 2) ? fry : 1.0f - fry)
                   * ((b & 4) ? frz : 1.0f - frz);

    // fine levels (l=5..15): frac==0, single gather
    const unsigned kyp = ky * cP1;
    const unsigned kzp = kz * cP2;
    unsigned gfu[11];
    float2   gff[11];
    #pragma unroll
    for (int l = 5; l < 16; ++l) {
        const int s = l - 5;
        const unsigned idx = ((kx << s) ^ (kyp << s) ^ (kzp << s)) & kMask;
        if (BT) gfu[l - 5] = tbx[(size_t)(l - 3) * kT + idx];
        else    gff[l - 5] = tbl[(size_t)l * kT + idx];
    }

    // hashed coarse (l=3,4): prefetch 16 gathers
    float2 gH[2][8];
    #pragma unroll
    for (int l = 3; l < 5; ++l) {
        const int d = 5 - l;
        const unsigned qx = kx >> d, qy = ky >> d, qz = kz >> d;
        const unsigned hy0 = qy * cP1, hy1 = hy0 + cP1;
        const unsigned hz0 = qz * cP2, hz1 = hz0 + cP2;
        const unsigned x1u = qx + 1u;
        unsigned hidx[8];
        hidx[0] = (qx  ^ hy0 ^ hz0) & kMask;  hidx[1] = (x1u ^ hy0 ^ hz0) & kMask;
        hidx[2] = (qx  ^ hy1 ^ hz0) & kMask;  hidx[3] = (x1u ^ hy1 ^ hz0) & kMask;
        hidx[4] = (qx  ^ hy0 ^ hz1) & kMask;  hidx[5] = (x1u ^ hy0 ^ hz1) & kMask;
        hidx[6] = (qx  ^ hy1 ^ hz1) & kMask;  hidx[7] = (x1u ^ hy1 ^ hz1) & kMask;
        if (BT) {
            const unsigned* __restrict__ base = tbx + (size_t)(l - 3) * kT;
            #pragma unroll
            for (int c = 0; c < 8; ++c) gH[l - 3][c] = bf2dec(base[hidx[c]]);
        } else {
            const float2* __restrict__ base = tbl + (size_t)l * kT;
            #pragma unroll
            for (int c = 0; c < 8; ++c) gH[l - 3][c] = base[hidx[c]];
        }
    }

    float2 gc[5];
    #pragma unroll
    for (int l = 0; l < 5; ++l) {
        const int d = 5 - l;
        const unsigned m = (1u << d) - 1u;
        const float inv = 1.0f / (float)(1 << d);
        const unsigned qx = kx >> d, qy = ky >> d, qz = kz >> d;
        const float fx = (float)(kx & m) * inv;
        const float fy = (float)(ky & m) * inv;
        const float fz = (float)(kz & m) * inv;
        float2 g0, g1, g2, g3, g4, g5, g6, g7;
        if (l < 3) {                     // dense fp32 (cache-resident), clamp
            const unsigned res = 16u << l;
            const unsigned R = res + 1u, R2 = R * R;
            const unsigned x0 = (qx < res ? qx : res);
            const unsigned x1 = (qx + 1u < res ? qx + 1u : res);
            const unsigned y0 = (qy < res ? qy : res) * R;
            const unsigned y1 = (qy + 1u < res ? qy + 1u : res) * R;
            const unsigned z0 = (qz < res ? qz : res) * R2;
            const unsigned z1 = (qz + 1u < res ? qz + 1u : res) * R2;
            const float2* __restrict__ base = tbl + (size_t)l * kT;
            g0 = base[x0 + y0 + z0]; g1 = base[x1 + y0 + z0];
            g2 = base[x0 + y1 + z0]; g3 = base[x1 + y1 + z0];
            g4 = base[x0 + y0 + z1]; g5 = base[x1 + y0 + z1];
            g6 = base[x0 + y1 + z1]; g7 = base[x1 + y1 + z1];
        } else {
            g0 = gH[l - 3][0]; g1 = gH[l - 3][1]; g2 = gH[l - 3][2]; g3 = gH[l - 3][3];
            g4 = gH[l - 3][4]; g5 = gH[l - 3][5]; g6 = gH[l - 3][6]; g7 = gH[l - 3][7];
        }
        const float wx1 = fx, wx0 = 1.0f - fx;
        const float wy1 = fy, wy0 = 1.0f - fy;
        const float wz1 = fz, wz0 = 1.0f - fz;
        const float w00 = wx0 * wy0, w10 = wx1 * wy0, w01 = wx0 * wy1, w11 = wx1 * wy1;
        const float a0 = w00 * wz0, a1 = w10 * wz0, a2 = w01 * wz0, a3 = w11 * wz0;
        const float a4 = w00 * wz1, a5 = w10 * wz1, a6 = w01 * wz1, a7 = w11 * wz1;
        float vx = a0 * g0.x + a1 * g1.x + a2 * g2.x + a3 * g3.x
                 + a4 * g4.x + a5 * g5.x + a6 * g6.x + a7 * g7.x;
        float vy = a0 * g0.y + a1 * g1.y + a2 * g2.y + a3 * g3.y
                 + a4 * g4.y + a5 * g5.y + a6 * g6.y + a7 * g7.y;
        gc[l] = make_float2(vx, vy);
    }

    // pack features: dword l = (bf16(f_{2l}), bf16(f_{2l+1}));
    // fine levels (BT): stored bf16 bits pass through unchanged (idempotent).
    unsigned xd[16];
    #pragma unroll
    for (int l = 0; l < 5; ++l)
        xd[l] = bf16_rn(gc[l].x) | (bf16_rn(gc[l].y) << 16);
    #pragma unroll
    for (int l = 5; l < 16; ++l) {
        if (BT) xd[l] = gfu[l - 5];
        else    xd[l] = bf16_rn(gff[l - 5].x) | (bf16_rn(gff[l - 5].y) << 16);
    }
    uint4* xr = (uint4*)(lds + tid * 16);
    xr[0] = make_uint4(xd[0],  xd[1],  xd[2],  xd[3]);
    xr[1] = make_uint4(xd[4],  xd[5],  xd[6],  xd[7]);
    xr[2] = make_uint4(xd[8],  xd[9],  xd[10], xd[11]);
    xr[3] = make_uint4(xd[12], xd[13], xd[14], xd[15]);

    __syncthreads();   // x + staged weights visible block-wide (barrier+fence)

    // ================= MLP (transposed MFMA, lane-local transitions) ======
    const short8_t* __restrict__ wl = (const short8_t*)(lds + WOFF);
    const int col = lane & 15;          // = eval within group = MFMA col
    const int q   = lane >> 4;
    const f32x4 zero = {0.0f, 0.0f, 0.0f, 0.0f};

    #pragma unroll 1
    for (int g = 0; g < 4; ++g) {
        const int ev = wv * 64 + g * 16 + col;
        const short8_t xb = *(const short8_t*)(lds + ev * 16 + q * 4);
        const float wbv = __shfl(wb, g * 16 + col, 64);   // wb of the source lane

        unsigned hp0[4], hp1[4];
        // layer 1: physical rows mt*16+q*4+r, eval col
        #pragma unroll
        for (int mt = 0; mt < 4; ++mt) {
            f32x4 a = mfma16(wl[mt * 64 + lane], xb, zero);
            hp0[mt] = bf16_rn(fmaxf(a[0], 0.0f)) | (bf16_rn(fmaxf(a[1], 0.0f)) << 16);
            hp1[mt] = bf16_rn(fmaxf(a[2], 0.0f)) | (bf16_rn(fmaxf(a[3], 0.0f)) << 16);
        }
        // lane-local B-frags (pi baked into W1's K-order in prep_w)
        uint4 u0 = make_uint4(hp0[0], hp1[0], hp0[1], hp1[1]);
        uint4 u1 = make_uint4(hp0[2], hp1[2], hp0[3], hp1[3]);
        short8_t bk0 = *(short8_t*)&u0;
        short8_t bk1 = *(short8_t*)&u1;

        // layer 2
        #pragma unroll
        for (int mt = 0; mt < 4; ++mt) {
            f32x4 a = mfma16(wl[(4 + mt * 2) * 64 + lane], bk0, zero);
            a = mfma16(wl[(5 + mt * 2) * 64 + lane], bk1, a);
            hp0[mt] = bf16_rn(fmaxf(a[0], 0.0f)) | (bf16_rn(fmaxf(a[1], 0.0f)) << 16);
            hp1[mt] = bf16_rn(fmaxf(a[2], 0.0f)) | (bf16_rn(fmaxf(a[3], 0.0f)) << 16);
        }
        u0 = make_uint4(hp0[0], hp1[0], hp0[1], hp1[1]);
        u1 = make_uint4(hp0[2], hp1[2], hp0[3], hp1[3]);
        bk0 = *(short8_t*)&u0;
        bk1 = *(short8_t*)&u1;

        // layer 3: out rows q*4+r (only q<2 real; W2 cols >=8 zero-padded)
        f32x4 a3 = mfma16(wl[12 * 64 + lane], bk0, zero);
        a3 = mfma16(wl[13 * 64 + lane], bk1, a3);

        // weight by wb and reduce over the 8 corners (eval low 3 bits)
        float v0 = wbv * a3[0], v1 = wbv * a3[1], v2 = wbv * a3[2], v3 = wbv * a3[3];
        #pragma unroll
        for (int s = 1; s < 8; s <<= 1) {
            v0 += __shfl_xor(v0, s);
            v1 += __shfl_xor(v1, s);
            v2 += __shfl_xor(v2, s);
            v3 += __shfl_xor(v3, s);
        }
        if (((lane & 7) == 0) && q < 2) {
            const int p = (blockIdx.x * BLOCK + ev) >> 3;
            *(float4*)(out + p * 8 + q * 4) = make_float4(v0, v1, v2, v3);
        }
    }
}

extern "C" void kernel_launch(void* const* d_in, const int* in_sizes, int n_in,
                              void* d_out, int out_size, void* d_ws, size_t ws_size,
                              hipStream_t stream) {
    const float*  xyz = (const float*)d_in[0];
    const float2* tbl = (const float2*)d_in[1];
    const float*  W0  = (const float*)d_in[2];
    const float*  W1  = (const float*)d_in[3];
    const float*  W2  = (const float*)d_in[4];
    const int*    bnd = (const int*)d_in[5];
    float* out = (float*)d_out;

    const int npts  = in_sizes[0] / 3;
    const int total = npts * 8;
    const int grid  = total / BLOCK;

    hipLaunchKernelGGL(prep_w, dim3(14), dim3(64), 0, stream,
                       W0, W1, W2, (uint4*)d_ws);

    if (ws_size >= WS_NEED) {
        // convert hashed levels 3..15 to packed bf16 (pairs of entries)
        const int pairs = 13 * (int)(kT / 2);           // 3,407,872
        hipLaunchKernelGGL(conv_t, dim3(pairs / 256), dim3(256), 0, stream,
                           (const float4*)(tbl + (size_t)3 * kT),
                           (uint2*)((unsigned*)d_ws + TOFF));
        hipLaunchKernelGGL(ngp_mfma<true>, dim3(grid), dim3(BLOCK), 0, stream,
                           xyz, tbl, bnd, (const unsigned*)d_ws, out, npts);
    } else {
        hipLaunchKernelGGL(ngp_mfma<false>, dim3(grid), dim3(BLOCK), 0, stream,
                           xyz, tbl, bnd, (const unsigned*)d_ws, out, npts);
    }
}

// Round 11
// 234.474 us; speedup vs baseline: 3.5219x; 1.5006x over previous
//
#include <hip/hip_runtime.h>

// Instant-NGP hash encode (16 levels, F=2) + 32->64->64->8 MLP via MFMA,
// outer trilinear over 8 corners of a 512^3 grid.
//
// R3-R6: MFMA MLP, lane-local layer transitions, spill-free.
// R7 FAILED (replay divergence, unroll-2): reverted; __syncthreads kept.
// R8/R9: weights in LDS, BLOCK 256 (occupancy 55%) — dur flat => L2-fill
//     traffic bound (~3.6 TB/s, dur tracks FETCH).
// R10: hashed levels bf16 in d_ws: FETCH -13%, dur -12% (law confirmed).
// R11: COMPACT the fine levels. idx = (X<<s)&mask has s low zero bits =>
//     level 5+s only touches stride-2^s entries (1 entry per 64B line for
//     s>=4). Store entry idx at idx>>s: active footprint 2MB/2^s, total
//     random region 26MB -> 8MB; levels >=8 (~0.5MB) become L2-resident.
//     Bit-identical values (pure relocation); idx' = X & (kMask>>s) also
//     drops 3 VALU/level. ws need: 16KB + 8MB.

typedef __attribute__((ext_vector_type(8))) short short8_t;
typedef __attribute__((ext_vector_type(4))) float f32x4;

static constexpr unsigned kT    = 1u << 19;
static constexpr unsigned kMask = kT - 1u;
static constexpr unsigned cP1   = 2654435761u;
static constexpr unsigned cP2   = 805459861u;
static constexpr int      BLOCK = 256;
static constexpr int      WOFF  = 4096;    // LDS dword offset of weight block
static constexpr int      TOFF  = 4096;    // d_ws dword offset of tables
static constexpr size_t   WS_NEED = ((size_t)TOFF + (1u << 21)) * 4;  // 16KB+8MB

static __device__ __forceinline__ unsigned bf16_rn(float x) {
    unsigned u = __float_as_uint(x);
    return (u + 0x7fffu + ((u >> 16) & 1u)) >> 16;   // round-to-nearest-even
}

static __device__ __forceinline__ float2 bf2dec(unsigned u) {
    return make_float2(__uint_as_float(u << 16),
                       __uint_as_float(u & 0xffff0000u));
}

static __device__ __forceinline__ f32x4 mfma16(short8_t a, short8_t b, f32x4 c) {
    return __builtin_amdgcn_mfma_f32_16x16x32_bf16(a, b, c, 0, 0, 0);
}

// ---- weight pre-swizzle: A-frag order, bf16 RNE, 14 tiles x 64 lanes x 16B.
// tiles: 0..3 = W0 (mt = t, K identity); 4..11 = W1 (mt=(t-4)>>1, kt=(t-4)&1);
//        12..13 = W2 (kt = t-12, cols m>=8 zeroed).
// W1/W2 K-index permuted by pi to match the lane-local D->B feed.
__global__ void prep_w(const float* __restrict__ W0, const float* __restrict__ W1,
                       const float* __restrict__ W2, uint4* __restrict__ ws)
{
    const int t = blockIdx.x, lane = threadIdx.x;
    const int n = lane & 15, q = lane >> 4;
    unsigned hi[4];
    #pragma unroll
    for (int d = 0; d < 4; ++d) {
        unsigned h2[2];
        #pragma unroll
        for (int s = 0; s < 2; ++s) {
            const int j = d * 2 + s;
            float v;
            if (t < 4) {
                v = W0[(q * 8 + j) * 64 + t * 16 + n];
            } else {
                const int kp = (j < 4) ? (q * 4 + j) : (16 + q * 4 + (j - 4));
                if (t < 12) v = W1[(((t - 4) & 1) * 32 + kp) * 64 + ((t - 4) >> 1) * 16 + n];
                else        v = (n < 8) ? W2[((t - 12) * 32 + kp) * 8 + n] : 0.0f;
            }
            h2[s] = bf16_rn(v);
        }
        hi[d] = h2[0] | (h2[1] << 16);
    }
    ws[t * 64 + lane] = make_uint4(hi[0], hi[1], hi[2], hi[3]);
}

// ---- coarse convert: levels 3,4 (2^20 entries) fp32x2 -> packed bf16x2
__global__ void conv_c(const float4* __restrict__ src, uint2* __restrict__ dst)
{
    const int i = blockIdx.x * 256 + threadIdx.x;   // pair of entries, < 2^19
    const float4 v = src[i];
    dst[i] = make_uint2(bf16_rn(v.x) | (bf16_rn(v.y) << 16),
                        bf16_rn(v.z) | (bf16_rn(v.w) << 16));
}

// ---- fine convert+compact: level 5+s entry (j<<s) -> compact slot j.
// Compact level base fineOff(s) = 2^20 - (2^20>>s); total 2^20-2^9 entries.
__global__ void conv_f(const float2* __restrict__ src, unsigned* __restrict__ dst)
{
    const int i = blockIdx.x * 256 + threadIdx.x;        // < 2^20 - 2^9
    const unsigned v = (1u << 20) - 1u - (unsigned)i;
    const int s = __clz((int)v) - 12;                    // 0..10
    const unsigned fo = (1u << 20) - ((1u << 20) >> s);
    const unsigned j = (unsigned)i - fo;
    const float2 e = src[((size_t)(5 + s) << 19) + ((size_t)j << s)];
    dst[i] = bf16_rn(e.x) | (bf16_rn(e.y) << 16);
}

template<bool BT>
__global__ __launch_bounds__(BLOCK, 5)
void ngp_mfma(const float*  __restrict__ xyz,
              const float2* __restrict__ tbl,
              const int*    __restrict__ boundp,
              const unsigned* __restrict__ wsw,
              float*        __restrict__ out,
              int npts)
{
    // LDS dwords: x [0,4096) eval stride 16dw (64B); weights [4096,7680).
    __shared__ __align__(16) unsigned lds[7680];
    const int tid  = threadIdx.x;
    const int lane = tid & 63;
    const int wv   = tid >> 6;

    // ---- stage weight block (14336 B = 896 uint4) into LDS, coalesced ----
    {
        const uint4* __restrict__ wsrc = (const uint4*)wsw;
        uint4* wdst = (uint4*)(lds + WOFF);
        #pragma unroll
        for (int k = 0; k < 4; ++k) {
            const int i = tid + k * 256;
            if (i < 896) wdst[i] = wsrc[i];
        }
    }

    // tables in ws: coarse l=3,4 at [0,2^20); compact fine at [2^20, ...)
    const unsigned* __restrict__ tbx = wsw + TOFF;

    // ================= encode =================
    const int ge = blockIdx.x * BLOCK + tid;
    const int pt = ge >> 3;
    const int b  = ge & 7;

    const float bnd = (float)boundp[0];
    const float sc  = 0.5f / bnd;

    const float pxv = xyz[pt * 3 + 0];
    const float pyv = xyz[pt * 3 + 1];
    const float pzv = xyz[pt * 3 + 2];

    const float cxf = (pxv + bnd) * sc * 512.0f;
    const float cyf = (pyv + bnd) * sc * 512.0f;
    const float czf = (pzv + bnd) * sc * 512.0f;

    const float c0x = fminf(fmaxf(floorf(cxf), 0.0f), 511.0f);
    const float c0y = fminf(fmaxf(floorf(cyf), 0.0f), 511.0f);
    const float c0z = fminf(fmaxf(floorf(czf), 0.0f), 511.0f);
    const float frx = cxf - c0x;
    const float fry = cyf - c0y;
    const float frz = czf - c0z;

    const unsigned kx = (unsigned)c0x + (unsigned)(b & 1);
    const unsigned ky = (unsigned)c0y + (unsigned)((b >> 1) & 1);
    const unsigned kz = (unsigned)c0z + (unsigned)((b >> 2) & 1);

    const float wb = ((b & 1) ? frx : 1.0f - frx)
                   * ((b & 2) ? fry : 1.0f - fry)
                   * ((b & 4) ? frz : 1.0f - frz);

    // fine levels (l=5..15): frac==0, single gather each.
    // idx = (X<<s)&kMask  =>  compact idx' = X & (kMask>>s).
    const unsigned kyp = ky * cP1;
    const unsigned kzp = kz * cP2;
    const unsigned X   = kx ^ kyp ^ kzp;
    unsigned gfu[11];
    float2   gff[11];
    #pragma unroll
    for (int l = 5; l < 16; ++l) {
        const int s = l - 5;
        if (BT) {
            const unsigned base = (1u << 20) + ((1u << 20) - ((1u << 20) >> s));
            gfu[l - 5] = tbx[base + (X & (kMask >> s))];
        } else {
            const unsigned idx = ((kx << s) ^ (kyp << s) ^ (kzp << s)) & kMask;
            gff[l - 5] = tbl[(size_t)l * kT + idx];
        }
    }

    // hashed coarse (l=3,4): prefetch 16 gathers
    float2 gH[2][8];
    #pragma unroll
    for (int l = 3; l < 5; ++l) {
        const int d = 5 - l;
        const unsigned qx = kx >> d, qy = ky >> d, qz = kz >> d;
        const unsigned hy0 = qy * cP1, hy1 = hy0 + cP1;
        const unsigned hz0 = qz * cP2, hz1 = hz0 + cP2;
        const unsigned x1u = qx + 1u;
        unsigned hidx[8];
        hidx[0] = (qx  ^ hy0 ^ hz0) & kMask;  hidx[1] = (x1u ^ hy0 ^ hz0) & kMask;
        hidx[2] = (qx  ^ hy1 ^ hz0) & kMask;  hidx[3] = (x1u ^ hy1 ^ hz0) & kMask;
        hidx[4] = (qx  ^ hy0 ^ hz1) & kMask;  hidx[5] = (x1u ^ hy0 ^ hz1) & kMask;
        hidx[6] = (qx  ^ hy1 ^ hz1) & kMask;  hidx[7] = (x1u ^ hy1 ^ hz1) & kMask;
        if (BT) {
            const unsigned* __restrict__ base = tbx + (size_t)(l - 3) * kT;
            #pragma unroll
            for (int c = 0; c < 8; ++c) gH[l - 3][c] = bf2dec(base[hidx[c]]);
        } else {
            const float2* __restrict__ base = tbl + (size_t)l * kT;
            #pragma unroll
            for (int c = 0; c < 8; ++c) gH[l - 3][c] = base[hidx[c]];
        }
    }

    float2 gc[5];
    #pragma unroll
    for (int l = 0; l < 5; ++l) {
        const int d = 5 - l;
        const unsigned m = (1u << d) - 1u;
        const float inv = 1.0f / (float)(1 << d);
        const unsigned qx = kx >> d, qy = ky >> d, qz = kz >> d;
        const float fx = (float)(kx & m) * inv;
        const float fy = (float)(ky & m) * inv;
        const float fz = (float)(kz & m) * inv;
        float2 g0, g1, g2, g3, g4, g5, g6, g7;
        if (l < 3) {                     // dense fp32 (cache-resident), clamp
            const unsigned res = 16u << l;
            const unsigned R = res + 1u, R2 = R * R;
            const unsigned x0 = (qx < res ? qx : res);
            const unsigned x1 = (qx + 1u < res ? qx + 1u : res);
            const unsigned y0 = (qy < res ? qy : res) * R;
            const unsigned y1 = (qy + 1u < res ? qy + 1u : res) * R;
            const unsigned z0 = (qz < res ? qz : res) * R2;
            const unsigned z1 = (qz + 1u < res ? qz + 1u : res) * R2;
            const float2* __restrict__ base = tbl + (size_t)l * kT;
            g0 = base[x0 + y0 + z0]; g1 = base[x1 + y0 + z0];
            g2 = base[x0 + y1 + z0]; g3 = base[x1 + y1 + z0];
            g4 = base[x0 + y0 + z1]; g5 = base[x1 + y0 + z1];
            g6 = base[x0 + y1 + z1]; g7 = base[x1 + y1 + z1];
        } else {
            g0 = gH[l - 3][0]; g1 = gH[l - 3][1]; g2 = gH[l - 3][2]; g3 = gH[l - 3][3];
            g4 = gH[l - 3][4]; g5 = gH[l - 3][5]; g6 = gH[l - 3][6]; g7 = gH[l - 3][7];
        }
        const float wx1 = fx, wx0 = 1.0f - fx;
        const float wy1 = fy, wy0 = 1.0f - fy;
        const float wz1 = fz, wz0 = 1.0f - fz;
        const float w00 = wx0 * wy0, w10 = wx1 * wy0, w01 = wx0 * wy1, w11 = wx1 * wy1;
        const float a0 = w00 * wz0, a1 = w10 * wz0, a2 = w01 * wz0, a3 = w11 * wz0;
        const float a4 = w00 * wz1, a5 = w10 * wz1, a6 = w01 * wz1, a7 = w11 * wz1;
        float vx = a0 * g0.x + a1 * g1.x + a2 * g2.x + a3 * g3.x
                 + a4 * g4.x + a5 * g5.x + a6 * g6.x + a7 * g7.x;
        float vy = a0 * g0.y + a1 * g1.y + a2 * g2.y + a3 * g3.y
                 + a4 * g4.y + a5 * g5.y + a6 * g6.y + a7 * g7.y;
        gc[l] = make_float2(vx, vy);
    }

    // pack features: dword l = (bf16(f_{2l}), bf16(f_{2l+1}));
    // fine levels (BT): stored bf16 bits pass through unchanged (idempotent).
    unsigned xd[16];
    #pragma unroll
    for (int l = 0; l < 5; ++l)
        xd[l] = bf16_rn(gc[l].x) | (bf16_rn(gc[l].y) << 16);
    #pragma unroll
    for (int l = 5; l < 16; ++l) {
        if (BT) xd[l] = gfu[l - 5];
        else    xd[l] = bf16_rn(gff[l - 5].x) | (bf16_rn(gff[l - 5].y) << 16);
    }
    uint4* xr = (uint4*)(lds + tid * 16);
    xr[0] = make_uint4(xd[0],  xd[1],  xd[2],  xd[3]);
    xr[1] = make_uint4(xd[4],  xd[5],  xd[6],  xd[7]);
    xr[2] = make_uint4(xd[8],  xd[9],  xd[10], xd[11]);
    xr[3] = make_uint4(xd[12], xd[13], xd[14], xd[15]);

    __syncthreads();   // x + staged weights visible block-wide (barrier+fence)

    // ================= MLP (transposed MFMA, lane-local transitions) ======
    const short8_t* __restrict__ wl = (const short8_t*)(lds + WOFF);
    const int col = lane & 15;          // = eval within group = MFMA col
    const int q   = lane >> 4;
    const f32x4 zero = {0.0f, 0.0f, 0.0f, 0.0f};

    #pragma unroll 1
    for (int g = 0; g < 4; ++g) {
        const int ev = wv * 64 + g * 16 + col;
        const short8_t xb = *(const short8_t*)(lds + ev * 16 + q * 4);
        const float wbv = __shfl(wb, g * 16 + col, 64);   // wb of the source lane

        unsigned hp0[4], hp1[4];
        // layer 1: physical rows mt*16+q*4+r, eval col
        #pragma unroll
        for (int mt = 0; mt < 4; ++mt) {
            f32x4 a = mfma16(wl[mt * 64 + lane], xb, zero);
            hp0[mt] = bf16_rn(fmaxf(a[0], 0.0f)) | (bf16_rn(fmaxf(a[1], 0.0f)) << 16);
            hp1[mt] = bf16_rn(fmaxf(a[2], 0.0f)) | (bf16_rn(fmaxf(a[3], 0.0f)) << 16);
        }
        // lane-local B-frags (pi baked into W1's K-order in prep_w)
        uint4 u0 = make_uint4(hp0[0], hp1[0], hp0[1], hp1[1]);
        uint4 u1 = make_uint4(hp0[2], hp1[2], hp0[3], hp1[3]);
        short8_t bk0 = *(short8_t*)&u0;
        short8_t bk1 = *(short8_t*)&u1;

        // layer 2
        #pragma unroll
        for (int mt = 0; mt < 4; ++mt) {
            f32x4 a = mfma16(wl[(4 + mt * 2) * 64 + lane], bk0, zero);
            a = mfma16(wl[(5 + mt * 2) * 64 + lane], bk1, a);
            hp0[mt] = bf16_rn(fmaxf(a[0], 0.0f)) | (bf16_rn(fmaxf(a[1], 0.0f)) << 16);
            hp1[mt] = bf16_rn(fmaxf(a[2], 0.0f)) | (bf16_rn(fmaxf(a[3], 0.0f)) << 16);
        }
        u0 = make_uint4(hp0[0], hp1[0], hp0[1], hp1[1]);
        u1 = make_uint4(hp0[2], hp1[2], hp0[3], hp1[3]);
        bk0 = *(short8_t*)&u0;
        bk1 = *(short8_t*)&u1;

        // layer 3: out rows q*4+r (only q<2 real; W2 cols >=8 zero-padded)
        f32x4 a3 = mfma16(wl[12 * 64 + lane], bk0, zero);
        a3 = mfma16(wl[13 * 64 + lane], bk1, a3);

        // weight by wb and reduce over the 8 corners (eval low 3 bits)
        float v0 = wbv * a3[0], v1 = wbv * a3[1], v2 = wbv * a3[2], v3 = wbv * a3[3];
        #pragma unroll
        for (int s = 1; s < 8; s <<= 1) {
            v0 += __shfl_xor(v0, s);
            v1 += __shfl_xor(v1, s);
            v2 += __shfl_xor(v2, s);
            v3 += __shfl_xor(v3, s);
        }
        if (((lane & 7) == 0) && q < 2) {
            const int p = (blockIdx.x * BLOCK + ev) >> 3;
            *(float4*)(out + p * 8 + q * 4) = make_float4(v0, v1, v2, v3);
        }
    }
}

extern "C" void kernel_launch(void* const* d_in, const int* in_sizes, int n_in,
                              void* d_out, int out_size, void* d_ws, size_t ws_size,
                              hipStream_t stream) {
    const float*  xyz = (const float*)d_in[0];
    const float2* tbl = (const float2*)d_in[1];
    const float*  W0  = (const float*)d_in[2];
    const float*  W1  = (const float*)d_in[3];
    const float*  W2  = (const float*)d_in[4];
    const int*    bnd = (const int*)d_in[5];
    float* out = (float*)d_out;

    const int npts  = in_sizes[0] / 3;
    const int total = npts * 8;
    const int grid  = total / BLOCK;

    hipLaunchKernelGGL(prep_w, dim3(14), dim3(64), 0, stream,
                       W0, W1, W2, (uint4*)d_ws);

    if (ws_size >= WS_NEED) {
        unsigned* tbx = (unsigned*)d_ws + TOFF;
        // coarse levels 3,4: plain bf16 convert (2^20 entries, pairs)
        hipLaunchKernelGGL(conv_c, dim3((1 << 19) / 256), dim3(256), 0, stream,
                           (const float4*)(tbl + (size_t)3 * kT), (uint2*)tbx);
        // fine levels 5..15: convert + stride-2^s compaction
        hipLaunchKernelGGL(conv_f, dim3(((1 << 20) - (1 << 9)) / 256), dim3(256),
                           0, stream, tbl, tbx + (1 << 20));
        hipLaunchKernelGGL(ngp_mfma<true>, dim3(grid), dim3(BLOCK), 0, stream,
                           xyz, tbl, bnd, (const unsigned*)d_ws, out, npts);
    } else {
        hipLaunchKernelGGL(ngp_mfma<false>, dim3(grid), dim3(BLOCK), 0, stream,
                           xyz, tbl, bnd, (const unsigned*)d_ws, out, npts);
    }
}